// Round 14
// baseline (193.704 us; speedup 1.0000x reference)
//
#include <hip/hip_runtime.h>
#include <hip/hip_bf16.h>
#include <cstdint>
#include <cstddef>

#define N_FEAT 512
#define N_HID 64
#define N_CLASS 16
#define N_CLUSTER 32
#define NPART 8          // privatized histogram partitions

typedef short short8 __attribute__((ext_vector_type(8)));
typedef float floatx4 __attribute__((ext_vector_type(4)));
typedef unsigned short u16;
typedef unsigned short u16x4 __attribute__((ext_vector_type(4)));

__device__ __forceinline__ short f2bf(float f) {
  __hip_bfloat16 h = __float2bfloat16(f);   // RNE
  return *reinterpret_cast<short*>(&h);
}
__device__ __forceinline__ u16 f2bfu(float f) { return (u16)f2bf(f); }
__device__ __forceinline__ float bf2f(u16 u) {
  return __uint_as_float((unsigned)u << 16);
}

// ---------------- W[K][64] fp32 -> BF in MFMA-fragment order (bf16), granule body ----
__device__ __forceinline__ void prepBF_one(const float* __restrict__ W,
                                           short* __restrict__ BF, int K, int idx) {
  int lane = idx & 63;
  int sj = idx >> 6;
  int j = sj & 3, s = sj >> 2;
  int col = j * 16 + (lane & 15);
  int k0 = s * 32 + ((lane >> 4) << 3);
  short8 v;
  #pragma unroll
  for (int t = 0; t < 8; ++t) v[t] = f2bf(W[(size_t)(k0 + t) * 64 + col]);
  *(short8*)(BF + (size_t)idx * 8) = v;
}

// ---------------- merged init: zero hist + pre-pack both weight tables ----------------
__global__ void k_init(uint4* __restrict__ h16, int n16,
                       const float* __restrict__ W1, short* __restrict__ BF1,
                       const float* __restrict__ W2, short* __restrict__ BF2,
                       int nbZ) {
  int b = blockIdx.x, t = threadIdx.x;
  if (b < nbZ) {
    int i = b * 256 + t;
    if (i < n16) h16[i] = make_uint4(0u, 0u, 0u, 0u);
  } else if (b < nbZ + 16) {
    prepBF_one(W1, BF1, N_FEAT, (b - nbZ) * 256 + t);      // 4096 granules
  } else {
    int idx = (b - nbZ - 16) * 256 + t;
    if (idx < 512) prepBF_one(W2, BF2, N_HID, idx);        // 512 granules
  }
}

// ---------------- packed degree/count histogram: one u64 atomic per edge ----------------
__global__ void k_degcnt2(const int* __restrict__ col, const float* __restrict__ w,
                          unsigned long long* __restrict__ hist, int H, int E) {
  int e = blockIdx.x * 256 + threadIdx.x;
  if (e >= E) return;
  int p = blockIdx.x & (NPART - 1);
  int c = col[e];
  unsigned long long fx = (unsigned long long)__float2uint_rn(w[e] * 16777216.0f);
  atomicAdd(&hist[(size_t)p * H + c], (1ull << 40) | fx);
}

// ---------------- fold partitions + exclusive scan (merged) ----------------
__global__ __launch_bounds__(256) void k_redscan(
    const unsigned long long* __restrict__ hist, int H,
    float* __restrict__ dinv, int* __restrict__ off,
    int* __restrict__ bsum, int n) {
  __shared__ int sh[256];
  int t = threadIdx.x;
  int i = blockIdx.x * 256 + t;
  int v = 0;
  if (i < n) {
    unsigned long long tot = 0;
    #pragma unroll
    for (int p = 0; p < NPART; ++p) tot += hist[(size_t)p * H + i];
    v = (int)(tot >> 40);
    float wsum = (float)(tot & ((1ull << 40) - 1)) * 5.9604644775390625e-08f; // 2^-24
    dinv[i] = rsqrtf(1.0f + wsum);
  }
  sh[t] = v;
  __syncthreads();
  #pragma unroll
  for (int d = 1; d < 256; d <<= 1) {
    int x = 0;
    if (t >= d) x = sh[t - d];
    __syncthreads();
    if (t >= d) sh[t] += x;
    __syncthreads();
  }
  if (i < n) off[i] = sh[t] - v;
  if (t == 255) bsum[blockIdx.x] = sh[255];
}

__global__ __launch_bounds__(256) void k_scan2(const int* __restrict__ bsum,
                                               int* __restrict__ bsum2, int nb) {
  __shared__ int sh[256];
  int t = threadIdx.x;
  int v = (t < nb) ? bsum[t] : 0;
  sh[t] = v;
  __syncthreads();
  #pragma unroll
  for (int d = 1; d < 256; d <<= 1) {
    int x = 0;
    if (t >= d) x = sh[t - d];
    __syncthreads();
    if (t >= d) sh[t] += x;
    __syncthreads();
  }
  if (t < nb) bsum2[t] = sh[t] - v;
}

__global__ void k_scan3_initcur(int* __restrict__ off, const int* __restrict__ bsum2,
                                const unsigned long long* __restrict__ hist, int H,
                                int* __restrict__ cur, int n, int E) {
  int i = blockIdx.x * 256 + threadIdx.x;
  if (i < n) {
    int o = off[i] + bsum2[blockIdx.x];
    off[i] = o;
    int running = o;
    #pragma unroll
    for (int p = 0; p < NPART; ++p) {
      cur[(size_t)p * H + i] = running;
      running += (int)(hist[(size_t)p * H + i] >> 40);
    }
  }
  if (i == 0) off[n] = E;
}

// ---------------- fill CSR slots: ONE 4B (src16 | coef-bf16) store per edge ----------------
__global__ void k_fill2(const int* __restrict__ rowi, const int* __restrict__ coli,
                        const float* __restrict__ w, const float* __restrict__ dinv,
                        int* __restrict__ cur, int H,
                        unsigned* __restrict__ pairs, int E) {
  int e = blockIdx.x * 256 + threadIdx.x;
  if (e >= E) return;
  int p = blockIdx.x & (NPART - 1);       // must match k_degcnt2's mapping
  int r = rowi[e], c = coli[e];
  int pos = atomicAdd(&cur[(size_t)p * H + c], 1);
  pairs[pos] = ((unsigned)r << 16) | (u16)f2bf(dinv[r] * w[e] * dinv[c]);
}

// ---------------- layer-1 GEMM with ADDRESS-ORDERED global reads ----------------
// Theory (R11 probe arithmetic): all prior variants visit each 2KB x-row in
// 128-256B slivers from ~50k interleaved streams -> DRAM row-activate thrash
// caps reads at ~1.3-2 TB/s (linear kernels: 7 TB/s). Here each block reads its
// 64-row x 2KB A-panel in EXACT address order (each wave = 1KB contiguous per
// instr, all 16 loads issued up-front), cvt to bf16, stage to LDS with the
// proven XOR-swizzle (k16 ^= row&7 -> conflict-free ds_read_b128), 1 barrier,
// then 8 waves x (16-row x 32-col) MFMA. B double-buffered from L2-hot BF.
__global__ __launch_bounds__(512, 4) void k_gemm512L(
    const float* __restrict__ A, const short8* __restrict__ BF,
    u16* __restrict__ C, int M) {
  __shared__ u16 Ls[64 * 512];             // 64 rows x 512 bf16 = 64 KB
  const int t = threadIdx.x;
  const int row0 = blockIdx.x * 64;

  // ---- stage: linear sweep of the 128KB fp32 panel (16 x 4KB instructions) ----
  float4 va[16];
  #pragma unroll
  for (int j = 0; j < 16; ++j) {
    int rl = j * 4 + (t >> 7);             // 0..63
    int grow = row0 + rl;
    if (grow >= M) grow = M - 1;           // duplicate row; C-write guarded
    va[j] = *(const float4*)(A + (size_t)grow * 512 + (t & 127) * 4);
  }
  __builtin_amdgcn_sched_barrier(0);       // keep the sweep issued up-front
  #pragma unroll
  for (int j = 0; j < 16; ++j) {
    int rl = j * 4 + (t >> 7);
    int k16 = (t & 127) >> 1;              // 16B granule within row (0..63)
    int pk = k16 ^ (rl & 7);               // m214 swizzle: row-major b128 reads
    u16x4 o;
    o[0] = f2bfu(va[j].x); o[1] = f2bfu(va[j].y);
    o[2] = f2bfu(va[j].z); o[3] = f2bfu(va[j].w);
    *(u16x4*)(Ls + rl * 512 + pk * 8 + (t & 1) * 4) = o;
  }
  __syncthreads();

  // ---- compute: wave w -> row-tile (w&3), col-half (w>>2) ----
  const int lane = t & 63;
  const int w = t >> 6;
  const int t4 = w & 3, ch = w >> 2;
  const int row_r = t4 * 16 + (lane & 15);
  const int xr = row_r & 7;
  const short8* bbase = BF + lane;

  short8 pb[2][2];
  #pragma unroll
  for (int s = 0; s < 2; ++s) {
    pb[s][0] = bbase[(s * 4 + 2 * ch) * 64];
    pb[s][1] = bbase[(s * 4 + 2 * ch + 1) * 64];
  }

  floatx4 acc[2];
  acc[0] = (floatx4){0.f, 0.f, 0.f, 0.f};
  acc[1] = (floatx4){0.f, 0.f, 0.f, 0.f};

  #pragma unroll
  for (int s = 0; s < 16; ++s) {
    const int sb = s & 1;
    int k16 = s * 4 + (lane >> 4);
    short8 af = *(const short8*)(Ls + row_r * 512 + (k16 ^ xr) * 8);
    acc[0] = __builtin_amdgcn_mfma_f32_16x16x32_bf16(af, pb[sb][0], acc[0], 0, 0, 0);
    acc[1] = __builtin_amdgcn_mfma_f32_16x16x32_bf16(af, pb[sb][1], acc[1], 0, 0, 0);
    if (s + 2 < 16) {
      pb[sb][0] = bbase[((s + 2) * 4 + 2 * ch) * 64];
      pb[sb][1] = bbase[((s + 2) * 4 + 2 * ch + 1) * 64];
    }
  }

  const int srow = row0 + t4 * 16 + (lane >> 4) * 4;
  const int scol = 2 * ch * 16 + (lane & 15);
  #pragma unroll
  for (int i = 0; i < 4; ++i) {
    int rr = srow + i;
    if (rr < M) {
      C[(size_t)rr * 64 + scol]      = f2bfu(acc[0][i]);
      C[(size_t)rr * 64 + scol + 16] = f2bfu(acc[1][i]);
    }
  }
}

// ---------------- layer-2 MFMA GEMM (K=64, bf16 A, L2-hot): register version ----------------
__global__ __launch_bounds__(64, 4) void k_mfma64(
    const u16* __restrict__ Av, const short8* __restrict__ BF,
    u16* __restrict__ C, int M) {
  const int lane = threadIdx.x & 63;
  const int rbase = blockIdx.x * 16;
  int r = rbase + (lane & 15);
  if (r >= M) r = M - 1;
  const int klo = (lane >> 4) * 8;
  const u16* arow = Av + (size_t)r * 64 + klo;
  const short8* bbase = BF + lane;

  short8 pah[2];
  short8 pb[2][4];
  pah[0] = *(const short8*)(arow);
  pah[1] = *(const short8*)(arow + 32);
  #pragma unroll
  for (int s = 0; s < 2; ++s)
    #pragma unroll
    for (int j = 0; j < 4; ++j)
      pb[s][j] = bbase[(s * 4 + j) * 64];

  floatx4 acc[4];
  #pragma unroll
  for (int j = 0; j < 4; ++j) acc[j] = (floatx4){0.f, 0.f, 0.f, 0.f};

  #pragma unroll
  for (int s = 0; s < 2; ++s) {
    acc[0] = __builtin_amdgcn_mfma_f32_16x16x32_bf16(pah[s], pb[s][0], acc[0], 0, 0, 0);
    acc[1] = __builtin_amdgcn_mfma_f32_16x16x32_bf16(pah[s], pb[s][1], acc[1], 0, 0, 0);
    acc[2] = __builtin_amdgcn_mfma_f32_16x16x32_bf16(pah[s], pb[s][2], acc[2], 0, 0, 0);
    acc[3] = __builtin_amdgcn_mfma_f32_16x16x32_bf16(pah[s], pb[s][3], acc[3], 0, 0, 0);
  }

  const int srow = rbase + (lane >> 4) * 4;
  const int scol = lane & 15;
  #pragma unroll
  for (int i = 0; i < 4; ++i) {
    int rr = srow + i;
    if (rr < M) {
      #pragma unroll
      for (int j = 0; j < 4; ++j)
        C[(size_t)rr * 64 + j * 16 + scol] = f2bfu(acc[j][i]);
    }
  }
}

// ---------------- gather conv: one wave per node, lane = feature dim ----------------
template<bool RELU>
__global__ __launch_bounds__(256) void k_gather(
    const int* __restrict__ off, const unsigned* __restrict__ pairs,
    const float* __restrict__ dinv,
    const u16* __restrict__ xw, const float* __restrict__ bias,
    u16* __restrict__ h, int n) {
  int gid = blockIdx.x * 256 + threadIdx.x;
  int c = gid >> 6, lane = gid & 63;
  if (c >= n) return;
  float s = dinv[c]; s *= s;
  float acc = fmaf(bf2f(xw[(size_t)c * 64 + lane]), s, bias[lane]);
  int i = off[c], end = off[c + 1];
  for (; i + 7 < end; i += 8) {
    unsigned p[8];
    float v[8];
    #pragma unroll
    for (int t = 0; t < 8; ++t) p[t] = pairs[i + t];
    #pragma unroll
    for (int t = 0; t < 8; ++t)
      v[t] = bf2f(xw[(size_t)(p[t] >> 16) * 64 + lane]);
    #pragma unroll
    for (int t = 0; t < 8; ++t)
      acc = fmaf(v[t], __uint_as_float((p[t] & 0xffffu) << 16), acc);
  }
  for (; i + 1 < end; i += 2) {
    unsigned p0 = pairs[i], p1 = pairs[i + 1];
    float v0 = bf2f(xw[(size_t)(p0 >> 16) * 64 + lane]);
    float v1 = bf2f(xw[(size_t)(p1 >> 16) * 64 + lane]);
    acc = fmaf(v0, __uint_as_float((p0 & 0xffffu) << 16), acc);
    acc = fmaf(v1, __uint_as_float((p1 & 0xffffu) << 16), acc);
  }
  if (i < end) {
    unsigned p = pairs[i];
    acc = fmaf(bf2f(xw[(size_t)(p >> 16) * 64 + lane]),
               __uint_as_float((p & 0xffffu) << 16), acc);
  }
  if (RELU) acc = fmaxf(acc, 0.f);
  h[(size_t)c * 64 + lane] = f2bfu(acc);
}

// ---------------- fused FC head (h in bf16) ----------------
__global__ __launch_bounds__(256) void k_fc(
    const u16* __restrict__ h,
    const float* __restrict__ fW1, const float* __restrict__ fb1,
    const float* __restrict__ fW2, const float* __restrict__ fb2,
    float* __restrict__ out, int M) {
  __shared__ float Hs[64][68];
  __shared__ float Ws[64][48];
  __shared__ float bs[48];
  const int t = threadIdx.x;
  const int row0 = blockIdx.x * 64;
  #pragma unroll
  for (int i = 0; i < 4; ++i) {
    int f = t + i * 256;
    int r = f >> 4, k4 = f & 15;
    int rr = row0 + r;
    float4 v = make_float4(0.f, 0.f, 0.f, 0.f);
    if (rr < M) {
      u16x4 u = *(const u16x4*)&h[(size_t)rr * 64 + k4 * 4];
      v = make_float4(bf2f(u[0]), bf2f(u[1]), bf2f(u[2]), bf2f(u[3]));
    }
    *(float4*)&Hs[r][k4 * 4] = v;
  }
  for (int f = t; f < 64 * 48; f += 256) {
    int k = f / 48, c = f - k * 48;
    Ws[k][c] = (c < 16) ? fW1[k * 16 + c] : fW2[k * 32 + (c - 16)];
  }
  if (t < 48) bs[t] = (t < 16) ? fb1[t] : fb2[t - 16];
  __syncthreads();
  const int tr = t >> 4, tc = t & 15;
  float acc[4][3] = {{0.f}};
  #pragma unroll 8
  for (int k = 0; k < 64; ++k) {
    float a[4], b[3];
    #pragma unroll
    for (int i = 0; i < 4; ++i) a[i] = Hs[tr * 4 + i][k];
    #pragma unroll
    for (int j = 0; j < 3; ++j) b[j] = Ws[k][tc * 3 + j];
    #pragma unroll
    for (int i = 0; i < 4; ++i)
      #pragma unroll
      for (int j = 0; j < 3; ++j) acc[i][j] = fmaf(a[i], b[j], acc[i][j]);
  }
  #pragma unroll
  for (int i = 0; i < 4; ++i) {
    int rr = row0 + tr * 4 + i;
    if (rr >= M) continue;
    #pragma unroll
    for (int j = 0; j < 3; ++j) {
      int c = tc * 3 + j;
      float v = acc[i][j] + bs[c];
      if (c < 16) out[(size_t)rr * 16 + c] = v;
      else out[(size_t)M * 16 + (size_t)rr * 32 + (c - 16)] = v;
    }
  }
}

extern "C" void kernel_launch(void* const* d_in, const int* in_sizes, int n_in,
                              void* d_out, int out_size, void* d_ws, size_t ws_size,
                              hipStream_t stream) {
  const float* x    = (const float*)d_in[0];
  const int*   ei   = (const int*)d_in[1];
  const float* ew   = (const float*)d_in[2];
  const float* W1   = (const float*)d_in[3];
  const float* b1   = (const float*)d_in[4];
  const float* W2   = (const float*)d_in[5];
  const float* b2   = (const float*)d_in[6];
  const float* fW1  = (const float*)d_in[7];
  const float* fb1  = (const float*)d_in[8];
  const float* fW2  = (const float*)d_in[9];
  const float* fb2  = (const float*)d_in[10];
  float* out = (float*)d_out;

  const int N = in_sizes[0] / N_FEAT;      // 50000 < 65536 (16-bit src pack)
  const int E = in_sizes[2];
  const int H = (N + 63) & ~63;
  const int* row = ei;
  const int* col = ei + E;

  char* ws = (char*)d_ws;
  float*              dinv = (float*)(ws + 0x000000);               // N f
  int*                off  = (int*)  (ws + 0x080000);               // N+1 i
  int*                bsum = (int*)  (ws + 0x0C0000);
  int*                bsum2= (int*)  (ws + 0x0C1000);
  short*              BF1  = (short*)(ws + 0x0C8000);               // 64KB frag-order B1
  short*              BF2  = (short*)(ws + 0x0DA000);               // 8KB frag-order B2
  unsigned long long* hist = (unsigned long long*)(ws + 0x100000);  // 8*H u64 (3.2MB)
  int*                cur  = (int*)  (ws + 0x500000);               // 8*H i (1.6MB)
  unsigned*           pairs= (unsigned*)(ws + 0x6C0000);            // E u32 (3.2MB)
  u16*                bufA = (u16*)  (ws + 0xD40000);               // N*64 bf16 (6.4MB)
  u16*                bufB = (u16*)  (ws + 0x1980000);              // N*64 bf16 (6.4MB)

  const int nbN  = (N + 255) / 256;
  const int nbE  = (E + 255) / 256;
  const int nbS  = (N + 63) / 64;          // 64-row GEMM blocks (782)
  const int nbT  = (N + 15) / 16;          // 16-row tiles (3125)
  const int nbG  = (N + 63) / 64;
  const int nbW  = (N * 64 + 255) / 256;
  const int nH16 = NPART * H / 2;          // hist size in uint4 units
  const int nbZ  = (nH16 + 255) / 256;

  // ---- init: zero hist + weight pre-pack (one dispatch) ----
  k_init<<<nbZ + 18, 256, 0, stream>>>((uint4*)hist, nH16, W1, BF1, W2, BF2, nbZ);

  // ---- degree histogram + normalization + CSR offsets + fill ----
  k_degcnt2<<<nbE, 256, 0, stream>>>(col, ew, hist, H, E);
  k_redscan<<<nbN, 256, 0, stream>>>(hist, H, dinv, off, bsum, N);
  k_scan2  <<<1,   256, 0, stream>>>(bsum, bsum2, nbN);
  k_scan3_initcur<<<nbN, 256, 0, stream>>>(off, bsum2, hist, H, cur, N, E);
  k_fill2  <<<nbE, 256, 0, stream>>>(row, col, ew, dinv, cur, H, pairs, E);

  // ---- layer 1: xw1 = x@W1 (address-ordered staged MFMA); h1 = relu(conv) ----
  k_gemm512L<<<nbS, 512, 0, stream>>>(x, (const short8*)BF1, bufA, N);
  k_gather<true><<<nbW, 256, 0, stream>>>(off, pairs, dinv, bufA, b1, bufB, N);

  // ---- layer 2: xw2 = h1@W2; h2 = conv ----
  k_mfma64<<<nbT, 64, 0, stream>>>(bufB, (const short8*)BF2, bufA, N);
  k_gather<false><<<nbW, 256, 0, stream>>>(off, pairs, dinv, bufA, b2, bufB, N);

  // ---- FC heads ----
  k_fc<<<nbG, 256, 0, stream>>>(bufB, fW1, fb1, fW2, fb2, out, N);
}

// Round 15
// 186.032 us; speedup vs baseline: 1.0412x; 1.0412x over previous
//
#include <hip/hip_runtime.h>
#include <hip/hip_bf16.h>
#include <cstdint>
#include <cstddef>

#define N_FEAT 512
#define N_HID 64
#define N_CLASS 16
#define N_CLUSTER 32
#define NPART 8          // privatized histogram partitions

typedef short short8 __attribute__((ext_vector_type(8)));
typedef float floatx4 __attribute__((ext_vector_type(4)));
typedef unsigned short u16;
typedef unsigned short u16x4 __attribute__((ext_vector_type(4)));

__device__ __forceinline__ short f2bf(float f) {
  __hip_bfloat16 h = __float2bfloat16(f);   // RNE
  return *reinterpret_cast<short*>(&h);
}
__device__ __forceinline__ u16 f2bfu(float f) { return (u16)f2bf(f); }
__device__ __forceinline__ float bf2f(u16 u) {
  return __uint_as_float((unsigned)u << 16);
}

// ---------------- W[K][64] fp32 -> BF in MFMA-fragment order (bf16), granule body ----
__device__ __forceinline__ void prepBF_one(const float* __restrict__ W,
                                           short* __restrict__ BF, int K, int idx) {
  int lane = idx & 63;
  int sj = idx >> 6;
  int j = sj & 3, s = sj >> 2;
  int col = j * 16 + (lane & 15);
  int k0 = s * 32 + ((lane >> 4) << 3);
  short8 v;
  #pragma unroll
  for (int t = 0; t < 8; ++t) v[t] = f2bf(W[(size_t)(k0 + t) * 64 + col]);
  *(short8*)(BF + (size_t)idx * 8) = v;
}

// ---------------- merged init: zero hist + pre-pack both weight tables ----------------
__global__ void k_init(uint4* __restrict__ h16, int n16,
                       const float* __restrict__ W1, short* __restrict__ BF1,
                       const float* __restrict__ W2, short* __restrict__ BF2,
                       int nbZ) {
  int b = blockIdx.x, t = threadIdx.x;
  if (b < nbZ) {
    int i = b * 256 + t;
    if (i < n16) h16[i] = make_uint4(0u, 0u, 0u, 0u);
  } else if (b < nbZ + 16) {
    prepBF_one(W1, BF1, N_FEAT, (b - nbZ) * 256 + t);      // 4096 granules
  } else {
    int idx = (b - nbZ - 16) * 256 + t;
    if (idx < 512) prepBF_one(W2, BF2, N_HID, idx);        // 512 granules
  }
}

// ---------------- fold partitions + exclusive scan (merged) ----------------
__global__ __launch_bounds__(256) void k_redscan(
    const unsigned long long* __restrict__ hist, int H,
    float* __restrict__ dinv, int* __restrict__ off,
    int* __restrict__ bsum, int n) {
  __shared__ int sh[256];
  int t = threadIdx.x;
  int i = blockIdx.x * 256 + t;
  int v = 0;
  if (i < n) {
    unsigned long long tot = 0;
    #pragma unroll
    for (int p = 0; p < NPART; ++p) tot += hist[(size_t)p * H + i];
    v = (int)(tot >> 40);
    float wsum = (float)(tot & ((1ull << 40) - 1)) * 5.9604644775390625e-08f; // 2^-24
    dinv[i] = rsqrtf(1.0f + wsum);
  }
  sh[t] = v;
  __syncthreads();
  #pragma unroll
  for (int d = 1; d < 256; d <<= 1) {
    int x = 0;
    if (t >= d) x = sh[t - d];
    __syncthreads();
    if (t >= d) sh[t] += x;
    __syncthreads();
  }
  if (i < n) off[i] = sh[t] - v;
  if (t == 255) bsum[blockIdx.x] = sh[255];
}

__global__ __launch_bounds__(256) void k_scan2(const int* __restrict__ bsum,
                                               int* __restrict__ bsum2, int nb) {
  __shared__ int sh[256];
  int t = threadIdx.x;
  int v = (t < nb) ? bsum[t] : 0;
  sh[t] = v;
  __syncthreads();
  #pragma unroll
  for (int d = 1; d < 256; d <<= 1) {
    int x = 0;
    if (t >= d) x = sh[t - d];
    __syncthreads();
    if (t >= d) sh[t] += x;
    __syncthreads();
  }
  if (t < nb) bsum2[t] = sh[t] - v;
}

__global__ void k_scan3_initcur(int* __restrict__ off, const int* __restrict__ bsum2,
                                const unsigned long long* __restrict__ hist, int H,
                                int* __restrict__ cur, int n, int E) {
  int i = blockIdx.x * 256 + threadIdx.x;
  if (i < n) {
    int o = off[i] + bsum2[blockIdx.x];
    off[i] = o;
    int running = o;
    #pragma unroll
    for (int p = 0; p < NPART; ++p) {
      cur[(size_t)p * H + i] = running;                 // read-only base for fill
      running += (int)(hist[(size_t)p * H + i] >> 40);
    }
  }
  if (i == 0) off[n] = E;
}

// ---------------- GEMM wave body: one 16-row x 64-col tile over K=512 ----------------
__device__ __forceinline__ void gemm_wave(
    const float* __restrict__ A, const short8* __restrict__ BF,
    u16* __restrict__ C, int M, int tile) {
  const int lane = threadIdx.x & 63;
  const int rbase = tile * 16;
  int r = rbase + (lane & 15);
  if (r >= M) r = M - 1;                    // only its own D-row is garbage
  const float* arow = A + (size_t)r * 512 + ((lane >> 4) << 3);
  const short8* bbase = BF + lane;

  float4 pa0[4], pa1[4];
  short8 pb[2][4];
  #pragma unroll
  for (int s = 0; s < 4; ++s) {
    pa0[s] = *(const float4*)(arow + s * 32);
    pa1[s] = *(const float4*)(arow + s * 32 + 4);
  }
  #pragma unroll
  for (int s = 0; s < 2; ++s)
    #pragma unroll
    for (int j = 0; j < 4; ++j)
      pb[s][j] = bbase[(s * 4 + j) * 64];
  __builtin_amdgcn_sched_barrier(0);        // prologue loads stay up-front

  floatx4 acc[4];
  #pragma unroll
  for (int j = 0; j < 4; ++j) acc[j] = (floatx4){0.f, 0.f, 0.f, 0.f};

  #pragma unroll
  for (int s = 0; s < 16; ++s) {
    const int sa = s & 3;
    const int sb = s & 1;
    float4 a0 = pa0[sa], a1 = pa1[sa];
    short8 af;
    af[0] = f2bf(a0.x); af[1] = f2bf(a0.y); af[2] = f2bf(a0.z); af[3] = f2bf(a0.w);
    af[4] = f2bf(a1.x); af[5] = f2bf(a1.y); af[6] = f2bf(a1.z); af[7] = f2bf(a1.w);
    acc[0] = __builtin_amdgcn_mfma_f32_16x16x32_bf16(af, pb[sb][0], acc[0], 0, 0, 0);
    acc[1] = __builtin_amdgcn_mfma_f32_16x16x32_bf16(af, pb[sb][1], acc[1], 0, 0, 0);
    acc[2] = __builtin_amdgcn_mfma_f32_16x16x32_bf16(af, pb[sb][2], acc[2], 0, 0, 0);
    acc[3] = __builtin_amdgcn_mfma_f32_16x16x32_bf16(af, pb[sb][3], acc[3], 0, 0, 0);
    if (s + 4 < 16) {
      pa0[sa] = *(const float4*)(arow + (s + 4) * 32);
      pa1[sa] = *(const float4*)(arow + (s + 4) * 32 + 4);
    }
    if (s + 2 < 16) {
      #pragma unroll
      for (int j = 0; j < 4; ++j)
        pb[sb][j] = bbase[((s + 2) * 4 + j) * 64];
    }
    __builtin_amdgcn_sched_barrier(0);      // refills can't sink past next MFMAs
  }

  const int srow = rbase + (lane >> 4) * 4;
  const int scol = lane & 15;
  #pragma unroll
  for (int i = 0; i < 4; ++i) {
    int rr = srow + i;
    if (rr < M) {
      #pragma unroll
      for (int j = 0; j < 4; ++j)
        C[(size_t)rr * 64 + j * 16 + scol] = f2bfu(acc[j][i]);
    }
  }
}

// ---------------- FUSED dispatch: gemm tiles || edge pass ----------------
// MODE 0 edge role: degcnt — u64 atomic per edge, returns old -> rank[e]
//                   (count field of old = within-(partition,target) rank).
// MODE 1 edge role: fill — NO atomics: pos = cur[p][c] + rank[e].
// Every (S+1)-th block runs 4 gemm_wave tiles; others process 256 edges.
template<int MODE>
__global__ __launch_bounds__(256, 4) void k_fused(
    const float* __restrict__ A, const short8* __restrict__ BF,
    u16* __restrict__ C, int M, int nbT, int tile0, int S,
    const int* __restrict__ rowi, const int* __restrict__ coli,
    const float* __restrict__ w,
    unsigned long long* __restrict__ hist, int* __restrict__ rank,
    const float* __restrict__ dinv, const int* __restrict__ cur,
    unsigned* __restrict__ pairs, int H, int E) {
  const int q = blockIdx.x / (S + 1);
  const int r = blockIdx.x % (S + 1);
  if (r == 0) {
    int tile = tile0 + q * 4 + (threadIdx.x >> 6);
    if (tile < nbT) gemm_wave(A, BF, C, M, tile);
  } else {
    int f = q * S + (r - 1);                 // edge-block index (p = f & 7)
    int e = f * 256 + threadIdx.x;
    if (e >= E) return;
    int p = f & (NPART - 1);
    int c = coli[e];
    if constexpr (MODE == 0) {
      unsigned long long fx = (unsigned long long)__float2uint_rn(w[e] * 16777216.0f);
      unsigned long long old = atomicAdd(&hist[(size_t)p * H + c], (1ull << 40) | fx);
      rank[e] = (int)(old >> 40);
    } else {
      int rr = rowi[e];
      int pos = cur[(size_t)p * H + c] + rank[e];
      pairs[pos] = ((unsigned)rr << 16) | (u16)f2bf(dinv[rr] * w[e] * dinv[c]);
    }
  }
}

// ---------------- layer-2 MFMA GEMM (K=64, bf16 A, L2-hot): register version ----------------
__global__ __launch_bounds__(64, 4) void k_mfma64(
    const u16* __restrict__ Av, const short8* __restrict__ BF,
    u16* __restrict__ C, int M) {
  const int lane = threadIdx.x & 63;
  const int rbase = blockIdx.x * 16;
  int r = rbase + (lane & 15);
  if (r >= M) r = M - 1;
  const int klo = (lane >> 4) * 8;
  const u16* arow = Av + (size_t)r * 64 + klo;
  const short8* bbase = BF + lane;

  short8 pah[2];
  short8 pb[2][4];
  pah[0] = *(const short8*)(arow);
  pah[1] = *(const short8*)(arow + 32);
  #pragma unroll
  for (int s = 0; s < 2; ++s)
    #pragma unroll
    for (int j = 0; j < 4; ++j)
      pb[s][j] = bbase[(s * 4 + j) * 64];

  floatx4 acc[4];
  #pragma unroll
  for (int j = 0; j < 4; ++j) acc[j] = (floatx4){0.f, 0.f, 0.f, 0.f};

  #pragma unroll
  for (int s = 0; s < 2; ++s) {
    acc[0] = __builtin_amdgcn_mfma_f32_16x16x32_bf16(pah[s], pb[s][0], acc[0], 0, 0, 0);
    acc[1] = __builtin_amdgcn_mfma_f32_16x16x32_bf16(pah[s], pb[s][1], acc[1], 0, 0, 0);
    acc[2] = __builtin_amdgcn_mfma_f32_16x16x32_bf16(pah[s], pb[s][2], acc[2], 0, 0, 0);
    acc[3] = __builtin_amdgcn_mfma_f32_16x16x32_bf16(pah[s], pb[s][3], acc[3], 0, 0, 0);
  }

  const int srow = rbase + (lane >> 4) * 4;
  const int scol = lane & 15;
  #pragma unroll
  for (int i = 0; i < 4; ++i) {
    int rr = srow + i;
    if (rr < M) {
      #pragma unroll
      for (int j = 0; j < 4; ++j)
        C[(size_t)rr * 64 + j * 16 + scol] = f2bfu(acc[j][i]);
    }
  }
}

// ---------------- gather conv: one wave per node, lane = feature dim ----------------
template<bool RELU>
__global__ __launch_bounds__(256) void k_gather(
    const int* __restrict__ off, const unsigned* __restrict__ pairs,
    const float* __restrict__ dinv,
    const u16* __restrict__ xw, const float* __restrict__ bias,
    u16* __restrict__ h, int n) {
  int gid = blockIdx.x * 256 + threadIdx.x;
  int c = gid >> 6, lane = gid & 63;
  if (c >= n) return;
  float s = dinv[c]; s *= s;
  float acc = fmaf(bf2f(xw[(size_t)c * 64 + lane]), s, bias[lane]);
  int i = off[c], end = off[c + 1];
  for (; i + 7 < end; i += 8) {
    unsigned p[8];
    float v[8];
    #pragma unroll
    for (int t = 0; t < 8; ++t) p[t] = pairs[i + t];
    #pragma unroll
    for (int t = 0; t < 8; ++t)
      v[t] = bf2f(xw[(size_t)(p[t] >> 16) * 64 + lane]);
    #pragma unroll
    for (int t = 0; t < 8; ++t)
      acc = fmaf(v[t], __uint_as_float((p[t] & 0xffffu) << 16), acc);
  }
  for (; i + 1 < end; i += 2) {
    unsigned p0 = pairs[i], p1 = pairs[i + 1];
    float v0 = bf2f(xw[(size_t)(p0 >> 16) * 64 + lane]);
    float v1 = bf2f(xw[(size_t)(p1 >> 16) * 64 + lane]);
    acc = fmaf(v0, __uint_as_float((p0 & 0xffffu) << 16), acc);
    acc = fmaf(v1, __uint_as_float((p1 & 0xffffu) << 16), acc);
  }
  if (i < end) {
    unsigned p = pairs[i];
    acc = fmaf(bf2f(xw[(size_t)(p >> 16) * 64 + lane]),
               __uint_as_float((p & 0xffffu) << 16), acc);
  }
  if (RELU) acc = fmaxf(acc, 0.f);
  h[(size_t)c * 64 + lane] = f2bfu(acc);
}

// ---------------- fused FC head (h in bf16) ----------------
__global__ __launch_bounds__(256) void k_fc(
    const u16* __restrict__ h,
    const float* __restrict__ fW1, const float* __restrict__ fb1,
    const float* __restrict__ fW2, const float* __restrict__ fb2,
    float* __restrict__ out, int M) {
  __shared__ float Hs[64][68];
  __shared__ float Ws[64][48];
  __shared__ float bs[48];
  const int t = threadIdx.x;
  const int row0 = blockIdx.x * 64;
  #pragma unroll
  for (int i = 0; i < 4; ++i) {
    int f = t + i * 256;
    int r = f >> 4, k4 = f & 15;
    int rr = row0 + r;
    float4 v = make_float4(0.f, 0.f, 0.f, 0.f);
    if (rr < M) {
      u16x4 u = *(const u16x4*)&h[(size_t)rr * 64 + k4 * 4];
      v = make_float4(bf2f(u[0]), bf2f(u[1]), bf2f(u[2]), bf2f(u[3]));
    }
    *(float4*)&Hs[r][k4 * 4] = v;
  }
  for (int f = t; f < 64 * 48; f += 256) {
    int k = f / 48, c = f - k * 48;
    Ws[k][c] = (c < 16) ? fW1[k * 16 + c] : fW2[k * 32 + (c - 16)];
  }
  if (t < 48) bs[t] = (t < 16) ? fb1[t] : fb2[t - 16];
  __syncthreads();
  const int tr = t >> 4, tc = t & 15;
  float acc[4][3] = {{0.f}};
  #pragma unroll 8
  for (int k = 0; k < 64; ++k) {
    float a[4], b[3];
    #pragma unroll
    for (int i = 0; i < 4; ++i) a[i] = Hs[tr * 4 + i][k];
    #pragma unroll
    for (int j = 0; j < 3; ++j) b[j] = Ws[k][tc * 3 + j];
    #pragma unroll
    for (int i = 0; i < 4; ++i)
      #pragma unroll
      for (int j = 0; j < 3; ++j) acc[i][j] = fmaf(a[i], b[j], acc[i][j]);
  }
  #pragma unroll
  for (int i = 0; i < 4; ++i) {
    int rr = row0 + tr * 4 + i;
    if (rr >= M) continue;
    #pragma unroll
    for (int j = 0; j < 3; ++j) {
      int c = tc * 3 + j;
      float v = acc[i][j] + bs[c];
      if (c < 16) out[(size_t)rr * 16 + c] = v;
      else out[(size_t)M * 16 + (size_t)rr * 32 + (c - 16)] = v;
    }
  }
}

extern "C" void kernel_launch(void* const* d_in, const int* in_sizes, int n_in,
                              void* d_out, int out_size, void* d_ws, size_t ws_size,
                              hipStream_t stream) {
  const float* x    = (const float*)d_in[0];
  const int*   ei   = (const int*)d_in[1];
  const float* ew   = (const float*)d_in[2];
  const float* W1   = (const float*)d_in[3];
  const float* b1   = (const float*)d_in[4];
  const float* W2   = (const float*)d_in[5];
  const float* b2   = (const float*)d_in[6];
  const float* fW1  = (const float*)d_in[7];
  const float* fb1  = (const float*)d_in[8];
  const float* fW2  = (const float*)d_in[9];
  const float* fb2  = (const float*)d_in[10];
  float* out = (float*)d_out;

  const int N = in_sizes[0] / N_FEAT;      // 50000 < 65536 (16-bit src pack)
  const int E = in_sizes[2];
  const int H = (N + 63) & ~63;
  const int* row = ei;
  const int* col = ei + E;

  char* ws = (char*)d_ws;
  float*              dinv = (float*)(ws + 0x000000);               // N f
  int*                off  = (int*)  (ws + 0x080000);               // N+1 i
  int*                bsum = (int*)  (ws + 0x0C0000);
  int*                bsum2= (int*)  (ws + 0x0C1000);
  short*              BF1  = (short*)(ws + 0x0C8000);               // 64KB frag-order B1
  short*              BF2  = (short*)(ws + 0x0DA000);               // 8KB frag-order B2
  unsigned long long* hist = (unsigned long long*)(ws + 0x100000);  // 8*H u64 (3.2MB)
  int*                cur  = (int*)  (ws + 0x500000);               // 8*H i (1.6MB)
  unsigned*           pairs= (unsigned*)(ws + 0x6C0000);            // E u32 (3.2MB)
  int*                rank = (int*)  (ws + 0xA00000);               // E i (3.2MB)
  u16*                bufA = (u16*)  (ws + 0xD40000);               // N*64 bf16 (6.4MB)
  u16*                bufB = (u16*)  (ws + 0x1980000);              // N*64 bf16 (6.4MB)

  const int nbN  = (N + 255) / 256;
  const int nbE  = (E + 255) / 256;        // 3125 edge blocks
  const int nbT  = (N + 15) / 16;          // 3125 gemm tiles
  const int nbG  = (N + 63) / 64;
  const int nbW  = (N * 64 + 255) / 256;
  const int nH16 = NPART * H / 2;          // hist size in uint4 units
  const int nbZ  = (nH16 + 255) / 256;

  // fused-dispatch geometry: A = degcnt || ~20% of gemm; B = fill || rest
  const int GA = 160;
  const int SA = (nbE + GA - 1) / GA;                // 20
  const int tilesA = GA * 4;                         // 640
  const int GB = (nbT - tilesA + 3) / 4;             // 622
  const int SB = (nbE + GB - 1) / GB;                // 6

  // ---- init: zero hist + weight pre-pack (one dispatch) ----
  k_init<<<nbZ + 18, 256, 0, stream>>>((uint4*)hist, nH16, W1, BF1, W2, BF2, nbZ);

  // ---- A: degcnt (+rank) || gemm tiles [0, 640) ----
  k_fused<0><<<GA * (SA + 1), 256, 0, stream>>>(
      x, (const short8*)BF1, bufA, N, nbT, 0, SA,
      row, col, ew, hist, rank, dinv, cur, pairs, H, E);

  // ---- normalization + CSR offsets (tiny) ----
  k_redscan<<<nbN, 256, 0, stream>>>(hist, H, dinv, off, bsum, N);
  k_scan2  <<<1,   256, 0, stream>>>(bsum, bsum2, nbN);
  k_scan3_initcur<<<nbN, 256, 0, stream>>>(off, bsum2, hist, H, cur, N, E);

  // ---- B: atomic-free fill || gemm tiles [640, nbT) ----
  k_fused<1><<<GB * (SB + 1), 256, 0, stream>>>(
      x, (const short8*)BF1, bufA, N, nbT, tilesA, SB,
      row, col, ew, hist, rank, dinv, cur, pairs, H, E);

  // ---- layer 1 conv: h1 = relu(gather) ----
  k_gather<true><<<nbW, 256, 0, stream>>>(off, pairs, dinv, bufA, b1, bufB, N);

  // ---- layer 2: xw2 = h1@W2; h2 = gather ----
  k_mfma64<<<nbT, 64, 0, stream>>>(bufB, (const short8*)BF2, bufA, N);
  k_gather<false><<<nbW, 256, 0, stream>>>(off, pairs, dinv, bufA, b2, bufB, N);

  // ---- FC heads ----
  k_fc<<<nbG, 256, 0, stream>>>(bufB, fW1, fb1, fW2, fb2, out, N);
}

// Round 16
// 172.689 us; speedup vs baseline: 1.1217x; 1.0773x over previous
//
#include <hip/hip_runtime.h>
#include <hip/hip_bf16.h>
#include <cstdint>
#include <cstddef>

#define N_FEAT 512
#define N_HID 64
#define N_CLASS 16
#define N_CLUSTER 32
#define NPART 8          // privatized histogram partitions

typedef short short8 __attribute__((ext_vector_type(8)));
typedef float floatx4 __attribute__((ext_vector_type(4)));
typedef unsigned short u16;
typedef unsigned short u16x4 __attribute__((ext_vector_type(4)));
typedef unsigned short u16x8 __attribute__((ext_vector_type(8)));

__device__ __forceinline__ short f2bf(float f) {
  __hip_bfloat16 h = __float2bfloat16(f);   // RNE
  return *reinterpret_cast<short*>(&h);
}
__device__ __forceinline__ u16 f2bfu(float f) { return (u16)f2bf(f); }
__device__ __forceinline__ float bf2f(u16 u) {
  return __uint_as_float((unsigned)u << 16);
}

// ---------------- W[K][64] fp32 -> BF in MFMA-fragment order (bf16), granule body ----
__device__ __forceinline__ void prepBF_one(const float* __restrict__ W,
                                           short* __restrict__ BF, int K, int idx) {
  int lane = idx & 63;
  int sj = idx >> 6;
  int j = sj & 3, s = sj >> 2;
  int col = j * 16 + (lane & 15);
  int k0 = s * 32 + ((lane >> 4) << 3);
  short8 v;
  #pragma unroll
  for (int t = 0; t < 8; ++t) v[t] = f2bf(W[(size_t)(k0 + t) * 64 + col]);
  *(short8*)(BF + (size_t)idx * 8) = v;
}

// ---------------- merged init: zero hist + pre-pack both weight tables ----------------
__global__ void k_init(uint4* __restrict__ h16, int n16,
                       const float* __restrict__ W1, short* __restrict__ BF1,
                       const float* __restrict__ W2, short* __restrict__ BF2,
                       int nbZ) {
  int b = blockIdx.x, t = threadIdx.x;
  if (b < nbZ) {
    int i = b * 256 + t;
    if (i < n16) h16[i] = make_uint4(0u, 0u, 0u, 0u);
  } else if (b < nbZ + 16) {
    prepBF_one(W1, BF1, N_FEAT, (b - nbZ) * 256 + t);      // 4096 granules
  } else {
    int idx = (b - nbZ - 16) * 256 + t;
    if (idx < 512) prepBF_one(W2, BF2, N_HID, idx);        // 512 granules
  }
}

// ---------------- FUSED A: degcnt(+rank)  ||  x -> bf16 convert ----------------
// Edge role (r==0): u64 atomic per edge; old count field = within-(p,c) rank.
// Convert role (r=1..4): linear streaming f2bf — same RNE the GEMM loop used,
// so downstream numerics are bit-identical. Both roles are independent.
__global__ __launch_bounds__(256, 4) void k_fusedA(
    const float* __restrict__ x, u16* __restrict__ xbf, int nf8,
    const int* __restrict__ coli, const float* __restrict__ w,
    unsigned long long* __restrict__ hist, int* __restrict__ rank,
    int H, int E, int nbE) {
  const int q = blockIdx.x / 5;
  const int r = blockIdx.x % 5;
  if (r == 0) {
    if (q >= nbE) return;
    int e = q * 256 + threadIdx.x;
    if (e >= E) return;
    int p = q & (NPART - 1);
    int c = coli[e];
    unsigned long long fx = (unsigned long long)__float2uint_rn(w[e] * 16777216.0f);
    unsigned long long old = atomicAdd(&hist[(size_t)p * H + c], (1ull << 40) | fx);
    rank[e] = (int)(old >> 40);
  } else {
    int i = (q * 4 + (r - 1)) * 256 + threadIdx.x;   // 8-float granule
    if (i >= nf8) return;
    float4 a0 = *(const float4*)(x + (size_t)i * 8);
    float4 a1 = *(const float4*)(x + (size_t)i * 8 + 4);
    u16x8 o;
    o[0] = f2bfu(a0.x); o[1] = f2bfu(a0.y); o[2] = f2bfu(a0.z); o[3] = f2bfu(a0.w);
    o[4] = f2bfu(a1.x); o[5] = f2bfu(a1.y); o[6] = f2bfu(a1.z); o[7] = f2bfu(a1.w);
    *(u16x8*)(xbf + (size_t)i * 8) = o;
  }
}

// ---------------- fold partitions + exclusive scan (merged) ----------------
__global__ __launch_bounds__(256) void k_redscan(
    const unsigned long long* __restrict__ hist, int H,
    float* __restrict__ dinv, int* __restrict__ off,
    int* __restrict__ bsum, int n) {
  __shared__ int sh[256];
  int t = threadIdx.x;
  int i = blockIdx.x * 256 + t;
  int v = 0;
  if (i < n) {
    unsigned long long tot = 0;
    #pragma unroll
    for (int p = 0; p < NPART; ++p) tot += hist[(size_t)p * H + i];
    v = (int)(tot >> 40);
    float wsum = (float)(tot & ((1ull << 40) - 1)) * 5.9604644775390625e-08f; // 2^-24
    dinv[i] = rsqrtf(1.0f + wsum);
  }
  sh[t] = v;
  __syncthreads();
  #pragma unroll
  for (int d = 1; d < 256; d <<= 1) {
    int x = 0;
    if (t >= d) x = sh[t - d];
    __syncthreads();
    if (t >= d) sh[t] += x;
    __syncthreads();
  }
  if (i < n) off[i] = sh[t] - v;
  if (t == 255) bsum[blockIdx.x] = sh[255];
}

__global__ __launch_bounds__(256) void k_scan2(const int* __restrict__ bsum,
                                               int* __restrict__ bsum2, int nb) {
  __shared__ int sh[256];
  int t = threadIdx.x;
  int v = (t < nb) ? bsum[t] : 0;
  sh[t] = v;
  __syncthreads();
  #pragma unroll
  for (int d = 1; d < 256; d <<= 1) {
    int x = 0;
    if (t >= d) x = sh[t - d];
    __syncthreads();
    if (t >= d) sh[t] += x;
    __syncthreads();
  }
  if (t < nb) bsum2[t] = sh[t] - v;
}

__global__ void k_scan3_initcur(int* __restrict__ off, const int* __restrict__ bsum2,
                                const unsigned long long* __restrict__ hist, int H,
                                int* __restrict__ cur, int n, int E) {
  int i = blockIdx.x * 256 + threadIdx.x;
  if (i < n) {
    int o = off[i] + bsum2[blockIdx.x];
    off[i] = o;
    int running = o;
    #pragma unroll
    for (int p = 0; p < NPART; ++p) {
      cur[(size_t)p * H + i] = running;                 // read-only base for fill
      running += (int)(hist[(size_t)p * H + i] >> 40);
    }
  }
  if (i == 0) off[n] = E;
}

// ---------------- GEMM wave body (bf16 A): one 16-row x 64-col tile, K=512 ----------------
// Pure load+MFMA: A fragments are direct short8 MFMA operands (no cvt chain).
__device__ __forceinline__ void gemm_wave_bf(
    const u16* __restrict__ A, const short8* __restrict__ BF,
    u16* __restrict__ C, int M, int tile) {
  const int lane = threadIdx.x & 63;
  const int rbase = tile * 16;
  int r = rbase + (lane & 15);
  if (r >= M) r = M - 1;                    // only its own D-row is garbage
  const u16* arow = A + (size_t)r * 512 + ((lane >> 4) << 3);
  const short8* bbase = BF + lane;

  short8 pa[4];
  short8 pb[2][4];
  #pragma unroll
  for (int s = 0; s < 4; ++s)
    pa[s] = *(const short8*)(arow + s * 32);
  #pragma unroll
  for (int s = 0; s < 2; ++s)
    #pragma unroll
    for (int j = 0; j < 4; ++j)
      pb[s][j] = bbase[(s * 4 + j) * 64];
  __builtin_amdgcn_sched_barrier(0);        // prologue loads stay up-front

  floatx4 acc[4];
  #pragma unroll
  for (int j = 0; j < 4; ++j) acc[j] = (floatx4){0.f, 0.f, 0.f, 0.f};

  #pragma unroll
  for (int s = 0; s < 16; ++s) {
    const int sa = s & 3;
    const int sb = s & 1;
    short8 af = pa[sa];
    acc[0] = __builtin_amdgcn_mfma_f32_16x16x32_bf16(af, pb[sb][0], acc[0], 0, 0, 0);
    acc[1] = __builtin_amdgcn_mfma_f32_16x16x32_bf16(af, pb[sb][1], acc[1], 0, 0, 0);
    acc[2] = __builtin_amdgcn_mfma_f32_16x16x32_bf16(af, pb[sb][2], acc[2], 0, 0, 0);
    acc[3] = __builtin_amdgcn_mfma_f32_16x16x32_bf16(af, pb[sb][3], acc[3], 0, 0, 0);
    if (s + 4 < 16)
      pa[sa] = *(const short8*)(arow + (s + 4) * 32);
    if (s + 2 < 16) {
      #pragma unroll
      for (int j = 0; j < 4; ++j)
        pb[sb][j] = bbase[((s + 2) * 4 + j) * 64];
    }
    __builtin_amdgcn_sched_barrier(0);      // refills can't sink past next MFMAs
  }

  const int srow = rbase + (lane >> 4) * 4;
  const int scol = lane & 15;
  #pragma unroll
  for (int i = 0; i < 4; ++i) {
    int rr = srow + i;
    if (rr < M) {
      #pragma unroll
      for (int j = 0; j < 4; ++j)
        C[(size_t)rr * 64 + j * 16 + scol] = f2bfu(acc[j][i]);
    }
  }
}

// ---------------- FUSED B: full GEMM (bf16 A)  ||  atomic-free fill ----------------
__global__ __launch_bounds__(256, 4) void k_fusedB(
    const u16* __restrict__ Abf, const short8* __restrict__ BF,
    u16* __restrict__ C, int M, int nbT, int S,
    const int* __restrict__ rowi, const int* __restrict__ coli,
    const float* __restrict__ w,
    const int* __restrict__ rank, const float* __restrict__ dinv,
    const int* __restrict__ cur, unsigned* __restrict__ pairs,
    int H, int E) {
  const int q = blockIdx.x / (S + 1);
  const int r = blockIdx.x % (S + 1);
  if (r == 0) {
    int tile = q * 4 + (threadIdx.x >> 6);
    if (tile < nbT) gemm_wave_bf(Abf, BF, C, M, tile);
  } else {
    int f = q * S + (r - 1);                 // edge-block index (p = f & 7)
    int e = f * 256 + threadIdx.x;
    if (e >= E) return;
    int p = f & (NPART - 1);
    int c = coli[e];
    int rr = rowi[e];
    int pos = cur[(size_t)p * H + c] + rank[e];
    pairs[pos] = ((unsigned)rr << 16) | (u16)f2bf(dinv[rr] * w[e] * dinv[c]);
  }
}

// ---------------- layer-2 MFMA GEMM (K=64, bf16 A, L2-hot): register version ----------------
__global__ __launch_bounds__(64, 4) void k_mfma64(
    const u16* __restrict__ Av, const short8* __restrict__ BF,
    u16* __restrict__ C, int M) {
  const int lane = threadIdx.x & 63;
  const int rbase = blockIdx.x * 16;
  int r = rbase + (lane & 15);
  if (r >= M) r = M - 1;
  const int klo = (lane >> 4) * 8;
  const u16* arow = Av + (size_t)r * 64 + klo;
  const short8* bbase = BF + lane;

  short8 pah[2];
  short8 pb[2][4];
  pah[0] = *(const short8*)(arow);
  pah[1] = *(const short8*)(arow + 32);
  #pragma unroll
  for (int s = 0; s < 2; ++s)
    #pragma unroll
    for (int j = 0; j < 4; ++j)
      pb[s][j] = bbase[(s * 4 + j) * 64];

  floatx4 acc[4];
  #pragma unroll
  for (int j = 0; j < 4; ++j) acc[j] = (floatx4){0.f, 0.f, 0.f, 0.f};

  #pragma unroll
  for (int s = 0; s < 2; ++s) {
    acc[0] = __builtin_amdgcn_mfma_f32_16x16x32_bf16(pah[s], pb[s][0], acc[0], 0, 0, 0);
    acc[1] = __builtin_amdgcn_mfma_f32_16x16x32_bf16(pah[s], pb[s][1], acc[1], 0, 0, 0);
    acc[2] = __builtin_amdgcn_mfma_f32_16x16x32_bf16(pah[s], pb[s][2], acc[2], 0, 0, 0);
    acc[3] = __builtin_amdgcn_mfma_f32_16x16x32_bf16(pah[s], pb[s][3], acc[3], 0, 0, 0);
  }

  const int srow = rbase + (lane >> 4) * 4;
  const int scol = lane & 15;
  #pragma unroll
  for (int i = 0; i < 4; ++i) {
    int rr = srow + i;
    if (rr < M) {
      #pragma unroll
      for (int j = 0; j < 4; ++j)
        C[(size_t)rr * 64 + j * 16 + scol] = f2bfu(acc[j][i]);
    }
  }
}

// ---------------- gather conv: one wave per node, lane = feature dim ----------------
template<bool RELU>
__global__ __launch_bounds__(256) void k_gather(
    const int* __restrict__ off, const unsigned* __restrict__ pairs,
    const float* __restrict__ dinv,
    const u16* __restrict__ xw, const float* __restrict__ bias,
    u16* __restrict__ h, int n) {
  int gid = blockIdx.x * 256 + threadIdx.x;
  int c = gid >> 6, lane = gid & 63;
  if (c >= n) return;
  float s = dinv[c]; s *= s;
  float acc = fmaf(bf2f(xw[(size_t)c * 64 + lane]), s, bias[lane]);
  int i = off[c], end = off[c + 1];
  for (; i + 7 < end; i += 8) {
    unsigned p[8];
    float v[8];
    #pragma unroll
    for (int t = 0; t < 8; ++t) p[t] = pairs[i + t];
    #pragma unroll
    for (int t = 0; t < 8; ++t)
      v[t] = bf2f(xw[(size_t)(p[t] >> 16) * 64 + lane]);
    #pragma unroll
    for (int t = 0; t < 8; ++t)
      acc = fmaf(v[t], __uint_as_float((p[t] & 0xffffu) << 16), acc);
  }
  for (; i + 1 < end; i += 2) {
    unsigned p0 = pairs[i], p1 = pairs[i + 1];
    float v0 = bf2f(xw[(size_t)(p0 >> 16) * 64 + lane]);
    float v1 = bf2f(xw[(size_t)(p1 >> 16) * 64 + lane]);
    acc = fmaf(v0, __uint_as_float((p0 & 0xffffu) << 16), acc);
    acc = fmaf(v1, __uint_as_float((p1 & 0xffffu) << 16), acc);
  }
  if (i < end) {
    unsigned p = pairs[i];
    acc = fmaf(bf2f(xw[(size_t)(p >> 16) * 64 + lane]),
               __uint_as_float((p & 0xffffu) << 16), acc);
  }
  if (RELU) acc = fmaxf(acc, 0.f);
  h[(size_t)c * 64 + lane] = f2bfu(acc);
}

// ---------------- fused FC head (h in bf16) ----------------
__global__ __launch_bounds__(256) void k_fc(
    const u16* __restrict__ h,
    const float* __restrict__ fW1, const float* __restrict__ fb1,
    const float* __restrict__ fW2, const float* __restrict__ fb2,
    float* __restrict__ out, int M) {
  __shared__ float Hs[64][68];
  __shared__ float Ws[64][48];
  __shared__ float bs[48];
  const int t = threadIdx.x;
  const int row0 = blockIdx.x * 64;
  #pragma unroll
  for (int i = 0; i < 4; ++i) {
    int f = t + i * 256;
    int r = f >> 4, k4 = f & 15;
    int rr = row0 + r;
    float4 v = make_float4(0.f, 0.f, 0.f, 0.f);
    if (rr < M) {
      u16x4 u = *(const u16x4*)&h[(size_t)rr * 64 + k4 * 4];
      v = make_float4(bf2f(u[0]), bf2f(u[1]), bf2f(u[2]), bf2f(u[3]));
    }
    *(float4*)&Hs[r][k4 * 4] = v;
  }
  for (int f = t; f < 64 * 48; f += 256) {
    int k = f / 48, c = f - k * 48;
    Ws[k][c] = (c < 16) ? fW1[k * 16 + c] : fW2[k * 32 + (c - 16)];
  }
  if (t < 48) bs[t] = (t < 16) ? fb1[t] : fb2[t - 16];
  __syncthreads();
  const int tr = t >> 4, tc = t & 15;
  float acc[4][3] = {{0.f}};
  #pragma unroll 8
  for (int k = 0; k < 64; ++k) {
    float a[4], b[3];
    #pragma unroll
    for (int i = 0; i < 4; ++i) a[i] = Hs[tr * 4 + i][k];
    #pragma unroll
    for (int j = 0; j < 3; ++j) b[j] = Ws[k][tc * 3 + j];
    #pragma unroll
    for (int i = 0; i < 4; ++i)
      #pragma unroll
      for (int j = 0; j < 3; ++j) acc[i][j] = fmaf(a[i], b[j], acc[i][j]);
  }
  #pragma unroll
  for (int i = 0; i < 4; ++i) {
    int rr = row0 + tr * 4 + i;
    if (rr >= M) continue;
    #pragma unroll
    for (int j = 0; j < 3; ++j) {
      int c = tc * 3 + j;
      float v = acc[i][j] + bs[c];
      if (c < 16) out[(size_t)rr * 16 + c] = v;
      else out[(size_t)M * 16 + (size_t)rr * 32 + (c - 16)] = v;
    }
  }
}

extern "C" void kernel_launch(void* const* d_in, const int* in_sizes, int n_in,
                              void* d_out, int out_size, void* d_ws, size_t ws_size,
                              hipStream_t stream) {
  const float* x    = (const float*)d_in[0];
  const int*   ei   = (const int*)d_in[1];
  const float* ew   = (const float*)d_in[2];
  const float* W1   = (const float*)d_in[3];
  const float* b1   = (const float*)d_in[4];
  const float* W2   = (const float*)d_in[5];
  const float* b2   = (const float*)d_in[6];
  const float* fW1  = (const float*)d_in[7];
  const float* fb1  = (const float*)d_in[8];
  const float* fW2  = (const float*)d_in[9];
  const float* fb2  = (const float*)d_in[10];
  float* out = (float*)d_out;

  const int N = in_sizes[0] / N_FEAT;      // 50000 < 65536 (16-bit src pack)
  const int E = in_sizes[2];
  const int H = (N + 63) & ~63;
  const int* row = ei;
  const int* col = ei + E;

  char* ws = (char*)d_ws;
  float*              dinv = (float*)(ws + 0x000000);               // N f
  int*                off  = (int*)  (ws + 0x080000);               // N+1 i
  int*                bsum = (int*)  (ws + 0x0C0000);
  int*                bsum2= (int*)  (ws + 0x0C1000);
  short*              BF1  = (short*)(ws + 0x0C8000);               // 64KB frag-order B1
  short*              BF2  = (short*)(ws + 0x0DA000);               // 8KB frag-order B2
  unsigned long long* hist = (unsigned long long*)(ws + 0x100000);  // 8*H u64 (3.2MB)
  int*                cur  = (int*)  (ws + 0x500000);               // 8*H i (1.6MB)
  unsigned*           pairs= (unsigned*)(ws + 0x6C0000);            // E u32 (3.2MB)
  int*                rank = (int*)  (ws + 0xA00000);               // E i (3.2MB)
  u16*                bufA = (u16*)  (ws + 0xD40000);               // N*64 bf16 (6.4MB)
  u16*                bufB = (u16*)  (ws + 0x1980000);              // N*64 bf16 (6.4MB)
  u16*                xbf  = (u16*)  (ws + 0x2400000);              // N*512 bf16 (51.2MB)

  const int nbN  = (N + 255) / 256;
  const int nbE  = (E + 255) / 256;        // 3125 edge blocks
  const int nbT  = (N + 15) / 16;          // 3125 gemm tiles
  const int nbG  = (N + 63) / 64;
  const int nbW  = (N * 64 + 255) / 256;
  const int nH16 = NPART * H / 2;          // hist size in uint4 units
  const int nbZ  = (nH16 + 255) / 256;
  const int nf8  = N * N_FEAT / 8;         // 8-float convert granules
  const int ncv  = (nf8 + 255) / 256;      // convert blocks (12500)

  // dispatch-A geometry: 1 edge block : 4 convert blocks
  const int QA = (nbE > (ncv + 3) / 4) ? nbE : (ncv + 3) / 4;
  // dispatch-B geometry: full gemm || fill
  const int GB = (nbT + 3) / 4;            // 782
  const int SB = (nbE + GB - 1) / GB;      // 4

  // ---- init: zero hist + weight pre-pack (one dispatch) ----
  k_init<<<nbZ + 18, 256, 0, stream>>>((uint4*)hist, nH16, W1, BF1, W2, BF2, nbZ);

  // ---- A: degcnt (+rank) || x -> bf16 convert ----
  k_fusedA<<<QA * 5, 256, 0, stream>>>(x, xbf, nf8, col, ew, hist, rank, H, E, nbE);

  // ---- normalization + CSR offsets (tiny) ----
  k_redscan<<<nbN, 256, 0, stream>>>(hist, H, dinv, off, bsum, N);
  k_scan2  <<<1,   256, 0, stream>>>(bsum, bsum2, nbN);
  k_scan3_initcur<<<nbN, 256, 0, stream>>>(off, bsum2, hist, H, cur, N, E);

  // ---- B: full GEMM (bf16 A, half the read bytes) || atomic-free fill ----
  k_fusedB<<<GB * (SB + 1), 256, 0, stream>>>(
      xbf, (const short8*)BF1, bufA, N, nbT, SB,
      row, col, ew, rank, dinv, cur, pairs, H, E);

  // ---- layer 1 conv: h1 = relu(gather) ----
  k_gather<true><<<nbW, 256, 0, stream>>>(off, pairs, dinv, bufA, b1, bufB, N);

  // ---- layer 2: xw2 = h1@W2; h2 = gather ----
  k_mfma64<<<nbT, 64, 0, stream>>>(bufB, (const short8*)BF2, bufA, N);
  k_gather<false><<<nbW, 256, 0, stream>>>(off, pairs, dinv, bufA, b2, bufB, N);

  // ---- FC heads ----
  k_fc<<<nbG, 256, 0, stream>>>(bufB, fW1, fb1, fW2, fb2, out, N);
}

// Round 17
// 172.216 us; speedup vs baseline: 1.1248x; 1.0027x over previous
//
#include <hip/hip_runtime.h>
#include <hip/hip_bf16.h>
#include <cstdint>
#include <cstddef>

#define N_FEAT 512
#define N_HID 64
#define N_CLASS 16
#define N_CLUSTER 32
#define NPART 8          // privatized histogram partitions

typedef short short8 __attribute__((ext_vector_type(8)));
typedef float floatx4 __attribute__((ext_vector_type(4)));
typedef unsigned short u16;
typedef unsigned short u16x4 __attribute__((ext_vector_type(4)));
typedef unsigned short u16x8 __attribute__((ext_vector_type(8)));

__device__ __forceinline__ short f2bf(float f) {
  __hip_bfloat16 h = __float2bfloat16(f);   // RNE
  return *reinterpret_cast<short*>(&h);
}
__device__ __forceinline__ u16 f2bfu(float f) { return (u16)f2bf(f); }
__device__ __forceinline__ float bf2f(u16 u) {
  return __uint_as_float((unsigned)u << 16);
}

// ---------------- W[K][64] fp32 -> BF in MFMA-fragment order (bf16), granule body ----
__device__ __forceinline__ void prepBF_one(const float* __restrict__ W,
                                           short* __restrict__ BF, int K, int idx) {
  int lane = idx & 63;
  int sj = idx >> 6;
  int j = sj & 3, s = sj >> 2;
  int col = j * 16 + (lane & 15);
  int k0 = s * 32 + ((lane >> 4) << 3);
  short8 v;
  #pragma unroll
  for (int t = 0; t < 8; ++t) v[t] = f2bf(W[(size_t)(k0 + t) * 64 + col]);
  *(short8*)(BF + (size_t)idx * 8) = v;
}

// ---------------- merged init: zero hist + pre-pack both weight tables ----------------
__global__ void k_init(uint4* __restrict__ h16, int n16,
                       const float* __restrict__ W1, short* __restrict__ BF1,
                       const float* __restrict__ W2, short* __restrict__ BF2,
                       int nbZ) {
  int b = blockIdx.x, t = threadIdx.x;
  if (b < nbZ) {
    int i = b * 256 + t;
    if (i < n16) h16[i] = make_uint4(0u, 0u, 0u, 0u);
  } else if (b < nbZ + 16) {
    prepBF_one(W1, BF1, N_FEAT, (b - nbZ) * 256 + t);      // 4096 granules
  } else {
    int idx = (b - nbZ - 16) * 256 + t;
    if (idx < 512) prepBF_one(W2, BF2, N_HID, idx);        // 512 granules
  }
}

// ---------------- FUSED A: degcnt(+rank)  ||  x -> xbf (bf16, MFMA-FRAGMENT order) ----
// Edge role (r==0): u64 atomic per edge; old count field = within-(p,c) rank.
// Tile role (r==1): one 16-row x 512-col tile: read fp32 linearly, cvt (same RNE
// as before -> numerics bit-identical), LDS transpose ([16][520] pad -> 2-way max),
// write xbf granules (tile,s,lane) CONTIGUOUSLY: xbf[tile*8192 + (s*64+lane)*8]
// holds A[tile*16+(lane&15)][s*32+(lane>>4)*8 .. +8) — the exact MFMA a-frag.
__global__ __launch_bounds__(256, 4) void k_fusedA(
    const float* __restrict__ x, u16* __restrict__ xbf, int M,
    const int* __restrict__ coli, const float* __restrict__ w,
    unsigned long long* __restrict__ hist, int* __restrict__ rank,
    int H, int E, int nbE, int nbT) {
  __shared__ u16 Ls[16 * 520];             // 16.25 KB, +8-short row pad
  const int q = blockIdx.x >> 1;
  const int r = blockIdx.x & 1;
  const int t = threadIdx.x;
  if (r == 0) {
    if (q >= nbE) return;
    int e = q * 256 + t;
    if (e >= E) return;
    int p = q & (NPART - 1);
    int c = coli[e];
    unsigned long long fx = (unsigned long long)__float2uint_rn(w[e] * 16777216.0f);
    unsigned long long old = atomicAdd(&hist[(size_t)p * H + c], (1ull << 40) | fx);
    rank[e] = (int)(old >> 40);
  } else {
    if (q >= nbT) return;
    const int row0 = q * 16;
    #pragma unroll
    for (int i = 0; i < 8; ++i) {
      int f = i * 256 + t;                 // 0..2047
      int row = f >> 7, c4 = f & 127;
      int grow = row0 + row;
      if (grow >= M) grow = M - 1;
      float4 v = *(const float4*)(x + (size_t)grow * 512 + c4 * 4);
      u16x4 o;
      o[0] = f2bfu(v.x); o[1] = f2bfu(v.y); o[2] = f2bfu(v.z); o[3] = f2bfu(v.w);
      *(u16x4*)(Ls + row * 520 + c4 * 4) = o;
    }
    __syncthreads();
    #pragma unroll
    for (int i = 0; i < 4; ++i) {
      int g = i * 256 + t;                 // 0..1023 granules
      int s = g >> 6, lane = g & 63;
      int row = lane & 15, k0 = s * 32 + ((lane >> 4) << 3);
      u16x8 v = *(const u16x8*)(Ls + row * 520 + k0);
      *(u16x8*)(xbf + (size_t)q * 8192 + (size_t)g * 8) = v;
    }
  }
}

// ---------------- fold partitions + exclusive scan (merged) ----------------
__global__ __launch_bounds__(256) void k_redscan(
    const unsigned long long* __restrict__ hist, int H,
    float* __restrict__ dinv, int* __restrict__ off,
    int* __restrict__ bsum, int n) {
  __shared__ int sh[256];
  int t = threadIdx.x;
  int i = blockIdx.x * 256 + t;
  int v = 0;
  if (i < n) {
    unsigned long long tot = 0;
    #pragma unroll
    for (int p = 0; p < NPART; ++p) tot += hist[(size_t)p * H + i];
    v = (int)(tot >> 40);
    float wsum = (float)(tot & ((1ull << 40) - 1)) * 5.9604644775390625e-08f; // 2^-24
    dinv[i] = rsqrtf(1.0f + wsum);
  }
  sh[t] = v;
  __syncthreads();
  #pragma unroll
  for (int d = 1; d < 256; d <<= 1) {
    int x = 0;
    if (t >= d) x = sh[t - d];
    __syncthreads();
    if (t >= d) sh[t] += x;
    __syncthreads();
  }
  if (i < n) off[i] = sh[t] - v;
  if (t == 255) bsum[blockIdx.x] = sh[255];
}

// ---------------- scan fixup + cursor bases (block-sum scan folded in) ----------------
__global__ __launch_bounds__(256) void k_scan3_initcur(
    int* __restrict__ off, const int* __restrict__ bsum,
    const unsigned long long* __restrict__ hist, int H,
    int* __restrict__ cur, int n, int E, int nb) {
  __shared__ int sh[256];
  int t = threadIdx.x;
  int v = (t < nb) ? bsum[t] : 0;
  sh[t] = v;
  __syncthreads();
  #pragma unroll
  for (int d = 1; d < 256; d <<= 1) {
    int x = 0;
    if (t >= d) x = sh[t - d];
    __syncthreads();
    if (t >= d) sh[t] += x;
    __syncthreads();
  }
  int base = (blockIdx.x > 0) ? sh[blockIdx.x - 1] : 0;   // inclusive scan -> excl base
  int i = blockIdx.x * 256 + t;
  if (i < n) {
    int o = off[i] + base;
    off[i] = o;
    int running = o;
    #pragma unroll
    for (int p = 0; p < NPART; ++p) {
      cur[(size_t)p * H + i] = running;                   // read-only base for fill
      running += (int)(hist[(size_t)p * H + i] >> 40);
    }
  }
  if (i == 0) off[n] = E;
}

// ---------------- GEMM wave body (fragment-order bf16 A): 16-row x 64-col, K=512 ----
// Every A-load is a CONTIGUOUS 1KB wave-read (zero fracture); pure load+MFMA.
__device__ __forceinline__ void gemm_wave_bf(
    const u16* __restrict__ A, const short8* __restrict__ BF,
    u16* __restrict__ C, int M, int tile) {
  const int lane = threadIdx.x & 63;
  const u16* abase = A + (size_t)tile * 8192 + lane * 8;
  const short8* bbase = BF + lane;

  short8 pa[4];
  short8 pb[2][4];
  #pragma unroll
  for (int s = 0; s < 4; ++s)
    pa[s] = *(const short8*)(abase + s * 512);
  #pragma unroll
  for (int s = 0; s < 2; ++s)
    #pragma unroll
    for (int j = 0; j < 4; ++j)
      pb[s][j] = bbase[(s * 4 + j) * 64];
  __builtin_amdgcn_sched_barrier(0);        // prologue loads stay up-front

  floatx4 acc[4];
  #pragma unroll
  for (int j = 0; j < 4; ++j) acc[j] = (floatx4){0.f, 0.f, 0.f, 0.f};

  #pragma unroll
  for (int s = 0; s < 16; ++s) {
    const int sa = s & 3;
    const int sb = s & 1;
    short8 af = pa[sa];
    acc[0] = __builtin_amdgcn_mfma_f32_16x16x32_bf16(af, pb[sb][0], acc[0], 0, 0, 0);
    acc[1] = __builtin_amdgcn_mfma_f32_16x16x32_bf16(af, pb[sb][1], acc[1], 0, 0, 0);
    acc[2] = __builtin_amdgcn_mfma_f32_16x16x32_bf16(af, pb[sb][2], acc[2], 0, 0, 0);
    acc[3] = __builtin_amdgcn_mfma_f32_16x16x32_bf16(af, pb[sb][3], acc[3], 0, 0, 0);
    if (s + 4 < 16)
      pa[sa] = *(const short8*)(abase + (s + 4) * 512);
    if (s + 2 < 16) {
      #pragma unroll
      for (int j = 0; j < 4; ++j)
        pb[sb][j] = bbase[((s + 2) * 4 + j) * 64];
    }
    __builtin_amdgcn_sched_barrier(0);      // refills can't sink past next MFMAs
  }

  const int srow = tile * 16 + (lane >> 4) * 4;
  const int scol = lane & 15;
  #pragma unroll
  for (int i = 0; i < 4; ++i) {
    int rr = srow + i;
    if (rr < M) {
      #pragma unroll
      for (int j = 0; j < 4; ++j)
        C[(size_t)rr * 64 + j * 16 + scol] = f2bfu(acc[j][i]);
    }
  }
}

// ---------------- FUSED B: full GEMM (frag-order bf16 A)  ||  atomic-free fill ----
__global__ __launch_bounds__(256, 4) void k_fusedB(
    const u16* __restrict__ Abf, const short8* __restrict__ BF,
    u16* __restrict__ C, int M, int nbT, int S,
    const int* __restrict__ rowi, const int* __restrict__ coli,
    const float* __restrict__ w,
    const int* __restrict__ rank, const float* __restrict__ dinv,
    const int* __restrict__ cur, unsigned* __restrict__ pairs,
    int H, int E) {
  const int q = blockIdx.x / (S + 1);
  const int r = blockIdx.x % (S + 1);
  if (r == 0) {
    int tile = q * 4 + (threadIdx.x >> 6);
    if (tile < nbT) gemm_wave_bf(Abf, BF, C, M, tile);
  } else {
    int f = q * S + (r - 1);                 // edge-block index (p = f & 7)
    int e = f * 256 + threadIdx.x;
    if (e >= E) return;
    int p = f & (NPART - 1);
    int c = coli[e];
    int rr = rowi[e];
    int pos = cur[(size_t)p * H + c] + rank[e];
    pairs[pos] = ((unsigned)rr << 16) | (u16)f2bf(dinv[rr] * w[e] * dinv[c]);
  }
}

// ---------------- layer-2 MFMA GEMM (K=64, bf16 A, L2-hot): register version ----------------
__global__ __launch_bounds__(64, 4) void k_mfma64(
    const u16* __restrict__ Av, const short8* __restrict__ BF,
    u16* __restrict__ C, int M) {
  const int lane = threadIdx.x & 63;
  const int rbase = blockIdx.x * 16;
  int r = rbase + (lane & 15);
  if (r >= M) r = M - 1;
  const int klo = (lane >> 4) * 8;
  const u16* arow = Av + (size_t)r * 64 + klo;
  const short8* bbase = BF + lane;

  short8 pah[2];
  short8 pb[2][4];
  pah[0] = *(const short8*)(arow);
  pah[1] = *(const short8*)(arow + 32);
  #pragma unroll
  for (int s = 0; s < 2; ++s)
    #pragma unroll
    for (int j = 0; j < 4; ++j)
      pb[s][j] = bbase[(s * 4 + j) * 64];

  floatx4 acc[4];
  #pragma unroll
  for (int j = 0; j < 4; ++j) acc[j] = (floatx4){0.f, 0.f, 0.f, 0.f};

  #pragma unroll
  for (int s = 0; s < 2; ++s) {
    acc[0] = __builtin_amdgcn_mfma_f32_16x16x32_bf16(pah[s], pb[s][0], acc[0], 0, 0, 0);
    acc[1] = __builtin_amdgcn_mfma_f32_16x16x32_bf16(pah[s], pb[s][1], acc[1], 0, 0, 0);
    acc[2] = __builtin_amdgcn_mfma_f32_16x16x32_bf16(pah[s], pb[s][2], acc[2], 0, 0, 0);
    acc[3] = __builtin_amdgcn_mfma_f32_16x16x32_bf16(pah[s], pb[s][3], acc[3], 0, 0, 0);
  }

  const int srow = rbase + (lane >> 4) * 4;
  const int scol = lane & 15;
  #pragma unroll
  for (int i = 0; i < 4; ++i) {
    int rr = srow + i;
    if (rr < M) {
      #pragma unroll
      for (int j = 0; j < 4; ++j)
        C[(size_t)rr * 64 + j * 16 + scol] = f2bfu(acc[j][i]);
    }
  }
}

// ---------------- gather conv: one wave per node, lane = feature dim ----------------
template<bool RELU>
__global__ __launch_bounds__(256) void k_gather(
    const int* __restrict__ off, const unsigned* __restrict__ pairs,
    const float* __restrict__ dinv,
    const u16* __restrict__ xw, const float* __restrict__ bias,
    u16* __restrict__ h, int n) {
  int gid = blockIdx.x * 256 + threadIdx.x;
  int c = gid >> 6, lane = gid & 63;
  if (c >= n) return;
  float s = dinv[c]; s *= s;
  float acc = fmaf(bf2f(xw[(size_t)c * 64 + lane]), s, bias[lane]);
  int i = off[c], end = off[c + 1];
  for (; i + 7 < end; i += 8) {
    unsigned p[8];
    float v[8];
    #pragma unroll
    for (int t = 0; t < 8; ++t) p[t] = pairs[i + t];
    #pragma unroll
    for (int t = 0; t < 8; ++t)
      v[t] = bf2f(xw[(size_t)(p[t] >> 16) * 64 + lane]);
    #pragma unroll
    for (int t = 0; t < 8; ++t)
      acc = fmaf(v[t], __uint_as_float((p[t] & 0xffffu) << 16), acc);
  }
  for (; i + 1 < end; i += 2) {
    unsigned p0 = pairs[i], p1 = pairs[i + 1];
    float v0 = bf2f(xw[(size_t)(p0 >> 16) * 64 + lane]);
    float v1 = bf2f(xw[(size_t)(p1 >> 16) * 64 + lane]);
    acc = fmaf(v0, __uint_as_float((p0 & 0xffffu) << 16), acc);
    acc = fmaf(v1, __uint_as_float((p1 & 0xffffu) << 16), acc);
  }
  if (i < end) {
    unsigned p = pairs[i];
    acc = fmaf(bf2f(xw[(size_t)(p >> 16) * 64 + lane]),
               __uint_as_float((p & 0xffffu) << 16), acc);
  }
  if (RELU) acc = fmaxf(acc, 0.f);
  h[(size_t)c * 64 + lane] = f2bfu(acc);
}

// ---------------- fused FC head (h in bf16) ----------------
__global__ __launch_bounds__(256) void k_fc(
    const u16* __restrict__ h,
    const float* __restrict__ fW1, const float* __restrict__ fb1,
    const float* __restrict__ fW2, const float* __restrict__ fb2,
    float* __restrict__ out, int M) {
  __shared__ float Hs[64][68];
  __shared__ float Ws[64][48];
  __shared__ float bs[48];
  const int t = threadIdx.x;
  const int row0 = blockIdx.x * 64;
  #pragma unroll
  for (int i = 0; i < 4; ++i) {
    int f = t + i * 256;
    int r = f >> 4, k4 = f & 15;
    int rr = row0 + r;
    float4 v = make_float4(0.f, 0.f, 0.f, 0.f);
    if (rr < M) {
      u16x4 u = *(const u16x4*)&h[(size_t)rr * 64 + k4 * 4];
      v = make_float4(bf2f(u[0]), bf2f(u[1]), bf2f(u[2]), bf2f(u[3]));
    }
    *(float4*)&Hs[r][k4 * 4] = v;
  }
  for (int f = t; f < 64 * 48; f += 256) {
    int k = f / 48, c = f - k * 48;
    Ws[k][c] = (c < 16) ? fW1[k * 16 + c] : fW2[k * 32 + (c - 16)];
  }
  if (t < 48) bs[t] = (t < 16) ? fb1[t] : fb2[t - 16];
  __syncthreads();
  const int tr = t >> 4, tc = t & 15;
  float acc[4][3] = {{0.f}};
  #pragma unroll 8
  for (int k = 0; k < 64; ++k) {
    float a[4], b[3];
    #pragma unroll
    for (int i = 0; i < 4; ++i) a[i] = Hs[tr * 4 + i][k];
    #pragma unroll
    for (int j = 0; j < 3; ++j) b[j] = Ws[k][tc * 3 + j];
    #pragma unroll
    for (int i = 0; i < 4; ++i)
      #pragma unroll
      for (int j = 0; j < 3; ++j) acc[i][j] = fmaf(a[i], b[j], acc[i][j]);
  }
  #pragma unroll
  for (int i = 0; i < 4; ++i) {
    int rr = row0 + tr * 4 + i;
    if (rr >= M) continue;
    #pragma unroll
    for (int j = 0; j < 3; ++j) {
      int c = tc * 3 + j;
      float v = acc[i][j] + bs[c];
      if (c < 16) out[(size_t)rr * 16 + c] = v;
      else out[(size_t)M * 16 + (size_t)rr * 32 + (c - 16)] = v;
    }
  }
}

extern "C" void kernel_launch(void* const* d_in, const int* in_sizes, int n_in,
                              void* d_out, int out_size, void* d_ws, size_t ws_size,
                              hipStream_t stream) {
  const float* x    = (const float*)d_in[0];
  const int*   ei   = (const int*)d_in[1];
  const float* ew   = (const float*)d_in[2];
  const float* W1   = (const float*)d_in[3];
  const float* b1   = (const float*)d_in[4];
  const float* W2   = (const float*)d_in[5];
  const float* b2   = (const float*)d_in[6];
  const float* fW1  = (const float*)d_in[7];
  const float* fb1  = (const float*)d_in[8];
  const float* fW2  = (const float*)d_in[9];
  const float* fb2  = (const float*)d_in[10];
  float* out = (float*)d_out;

  const int N = in_sizes[0] / N_FEAT;      // 50000 < 65536 (16-bit src pack)
  const int E = in_sizes[2];
  const int H = (N + 63) & ~63;
  const int* row = ei;
  const int* col = ei + E;

  char* ws = (char*)d_ws;
  float*              dinv = (float*)(ws + 0x000000);               // N f
  int*                off  = (int*)  (ws + 0x080000);               // N+1 i
  int*                bsum = (int*)  (ws + 0x0C0000);
  short*              BF1  = (short*)(ws + 0x0C8000);               // 64KB frag-order B1
  short*              BF2  = (short*)(ws + 0x0DA000);               // 8KB frag-order B2
  unsigned long long* hist = (unsigned long long*)(ws + 0x100000);  // 8*H u64 (3.2MB)
  int*                cur  = (int*)  (ws + 0x500000);               // 8*H i (1.6MB)
  unsigned*           pairs= (unsigned*)(ws + 0x6C0000);            // E u32 (3.2MB)
  int*                rank = (int*)  (ws + 0xA00000);               // E i (3.2MB)
  u16*                bufA = (u16*)  (ws + 0xD40000);               // N*64 bf16 (6.4MB)
  u16*                bufB = (u16*)  (ws + 0x1980000);              // N*64 bf16 (6.4MB)
  u16*                xbf  = (u16*)  (ws + 0x2400000);              // nbT*8192 bf16 (51.2MB)

  const int nbN  = (N + 255) / 256;
  const int nbE  = (E + 255) / 256;        // 3125 edge blocks
  const int nbT  = (N + 15) / 16;          // 3125 gemm tiles
  const int nbG  = (N + 63) / 64;
  const int nbW  = (N * 64 + 255) / 256;
  const int nH16 = NPART * H / 2;          // hist size in uint4 units
  const int nbZ  = (nH16 + 255) / 256;

  // dispatch-A geometry: 1 edge block : 1 transpose-tile block
  const int QA = (nbE > nbT) ? nbE : nbT;
  // dispatch-B geometry: full gemm || fill
  const int GB = (nbT + 3) / 4;            // 782
  const int SB = (nbE + GB - 1) / GB;      // 4

  // ---- init: zero hist + weight pre-pack (one dispatch) ----
  k_init<<<nbZ + 18, 256, 0, stream>>>((uint4*)hist, nH16, W1, BF1, W2, BF2, nbZ);

  // ---- A: degcnt (+rank) || x -> xbf (bf16, fragment order) ----
  k_fusedA<<<QA * 2, 256, 0, stream>>>(x, xbf, N, col, ew, hist, rank, H, E, nbE, nbT);

  // ---- normalization + CSR offsets (block-sum scan folded into scan3) ----
  k_redscan<<<nbN, 256, 0, stream>>>(hist, H, dinv, off, bsum, N);
  k_scan3_initcur<<<nbN, 256, 0, stream>>>(off, bsum, hist, H, cur, N, E, nbN);

  // ---- B: full GEMM (contiguous frag-order A) || atomic-free fill ----
  k_fusedB<<<GB * (SB + 1), 256, 0, stream>>>(
      xbf, (const short8*)BF1, bufA, N, nbT, SB,
      row, col, ew, rank, dinv, cur, pairs, H, E);

  // ---- layer 1 conv: h1 = relu(gather) ----
  k_gather<true><<<nbW, 256, 0, stream>>>(off, pairs, dinv, bufA, b1, bufB, N);

  // ---- layer 2: xw2 = h1@W2; h2 = gather ----
  k_mfma64<<<nbT, 64, 0, stream>>>(bufB, (const short8*)BF2, bufA, N);
  k_gather<false><<<nbW, 256, 0, stream>>>(off, pairs, dinv, bufA, b2, bufB, N);

  // ---- FC heads ----
  k_fc<<<nbG, 256, 0, stream>>>(bufB, fW1, fb1, fW2, fb2, out, N);
}

// Round 18
// 167.400 us; speedup vs baseline: 1.1571x; 1.0288x over previous
//
#include <hip/hip_runtime.h>
#include <hip/hip_bf16.h>
#include <cstdint>
#include <cstddef>

#define N_FEAT 512
#define N_HID 64
#define N_CLASS 16
#define N_CLUSTER 32
#define NPART 8          // privatized histogram partitions

typedef short short8 __attribute__((ext_vector_type(8)));
typedef float floatx4 __attribute__((ext_vector_type(4)));
typedef unsigned short u16;
typedef unsigned short u16x4 __attribute__((ext_vector_type(4)));
typedef unsigned short u16x8 __attribute__((ext_vector_type(8)));

__device__ __forceinline__ short f2bf(float f) {
  __hip_bfloat16 h = __float2bfloat16(f);   // RNE
  return *reinterpret_cast<short*>(&h);
}
__device__ __forceinline__ u16 f2bfu(float f) { return (u16)f2bf(f); }
__device__ __forceinline__ float bf2f(u16 u) {
  return __uint_as_float((unsigned)u << 16);
}

// ---------------- W[K][64] fp32 -> BF in MFMA-fragment order (bf16), granule body ----
__device__ __forceinline__ void prepBF_one(const float* __restrict__ W,
                                           short* __restrict__ BF, int K, int idx) {
  int lane = idx & 63;
  int sj = idx >> 6;
  int j = sj & 3, s = sj >> 2;
  int col = j * 16 + (lane & 15);
  int k0 = s * 32 + ((lane >> 4) << 3);
  short8 v;
  #pragma unroll
  for (int t = 0; t < 8; ++t) v[t] = f2bf(W[(size_t)(k0 + t) * 64 + col]);
  *(short8*)(BF + (size_t)idx * 8) = v;
}

// ---------------- merged init: zero hist + pre-pack both weight tables ----------------
__global__ void k_init(uint4* __restrict__ h16, int n16,
                       const float* __restrict__ W1, short* __restrict__ BF1,
                       const float* __restrict__ W2, short* __restrict__ BF2,
                       int nbZ) {
  int b = blockIdx.x, t = threadIdx.x;
  if (b < nbZ) {
    int i = b * 256 + t;
    if (i < n16) h16[i] = make_uint4(0u, 0u, 0u, 0u);
  } else if (b < nbZ + 16) {
    prepBF_one(W1, BF1, N_FEAT, (b - nbZ) * 256 + t);      // 4096 granules
  } else {
    int idx = (b - nbZ - 16) * 256 + t;
    if (idx < 512) prepBF_one(W2, BF2, N_HID, idx);        // 512 granules
  }
}

// ---------------- FUSED A: degcnt(+rank)  ||  x -> xbf (bf16, MFMA-FRAGMENT order) ----
__global__ __launch_bounds__(256, 4) void k_fusedA(
    const float* __restrict__ x, u16* __restrict__ xbf, int M,
    const int* __restrict__ coli, const float* __restrict__ w,
    unsigned long long* __restrict__ hist, int* __restrict__ rank,
    int H, int E, int nbE, int nbT) {
  __shared__ u16 Ls[16 * 520];             // 16.25 KB, +8-short row pad
  const int q = blockIdx.x >> 1;
  const int r = blockIdx.x & 1;
  const int t = threadIdx.x;
  if (r == 0) {
    if (q >= nbE) return;
    int e = q * 256 + t;
    if (e >= E) return;
    int p = q & (NPART - 1);
    int c = coli[e];
    unsigned long long fx = (unsigned long long)__float2uint_rn(w[e] * 16777216.0f);
    unsigned long long old = atomicAdd(&hist[(size_t)p * H + c], (1ull << 40) | fx);
    rank[e] = (int)(old >> 40);
  } else {
    if (q >= nbT) return;
    const int row0 = q * 16;
    #pragma unroll
    for (int i = 0; i < 8; ++i) {
      int f = i * 256 + t;                 // 0..2047
      int row = f >> 7, c4 = f & 127;
      int grow = row0 + row;
      if (grow >= M) grow = M - 1;
      float4 v = *(const float4*)(x + (size_t)grow * 512 + c4 * 4);
      u16x4 o;
      o[0] = f2bfu(v.x); o[1] = f2bfu(v.y); o[2] = f2bfu(v.z); o[3] = f2bfu(v.w);
      *(u16x4*)(Ls + row * 520 + c4 * 4) = o;
    }
    __syncthreads();
    #pragma unroll
    for (int i = 0; i < 4; ++i) {
      int g = i * 256 + t;                 // 0..1023 granules
      int s = g >> 6, lane = g & 63;
      int row = lane & 15, k0 = s * 32 + ((lane >> 4) << 3);
      u16x8 v = *(const u16x8*)(Ls + row * 520 + k0);
      *(u16x8*)(xbf + (size_t)q * 8192 + (size_t)g * 8) = v;
    }
  }
}

// ---------------- fold partitions + exclusive scan (merged) ----------------
__global__ __launch_bounds__(256) void k_redscan(
    const unsigned long long* __restrict__ hist, int H,
    float* __restrict__ dinv, int* __restrict__ off,
    int* __restrict__ bsum, int n) {
  __shared__ int sh[256];
  int t = threadIdx.x;
  int i = blockIdx.x * 256 + t;
  int v = 0;
  if (i < n) {
    unsigned long long tot = 0;
    #pragma unroll
    for (int p = 0; p < NPART; ++p) tot += hist[(size_t)p * H + i];
    v = (int)(tot >> 40);
    float wsum = (float)(tot & ((1ull << 40) - 1)) * 5.9604644775390625e-08f; // 2^-24
    dinv[i] = rsqrtf(1.0f + wsum);
  }
  sh[t] = v;
  __syncthreads();
  #pragma unroll
  for (int d = 1; d < 256; d <<= 1) {
    int x = 0;
    if (t >= d) x = sh[t - d];
    __syncthreads();
    if (t >= d) sh[t] += x;
    __syncthreads();
  }
  if (i < n) off[i] = sh[t] - v;
  if (t == 255) bsum[blockIdx.x] = sh[255];
}

// ---------------- scan fixup + cursor bases (block-sum scan folded in) ----------------
__global__ __launch_bounds__(256) void k_scan3_initcur(
    int* __restrict__ off, const int* __restrict__ bsum,
    const unsigned long long* __restrict__ hist, int H,
    int* __restrict__ cur, int n, int E, int nb) {
  __shared__ int sh[256];
  int t = threadIdx.x;
  int v = (t < nb) ? bsum[t] : 0;
  sh[t] = v;
  __syncthreads();
  #pragma unroll
  for (int d = 1; d < 256; d <<= 1) {
    int x = 0;
    if (t >= d) x = sh[t - d];
    __syncthreads();
    if (t >= d) sh[t] += x;
    __syncthreads();
  }
  int base = (blockIdx.x > 0) ? sh[blockIdx.x - 1] : 0;   // inclusive scan -> excl base
  int i = blockIdx.x * 256 + t;
  if (i < n) {
    int o = off[i] + base;
    off[i] = o;
    int running = o;
    #pragma unroll
    for (int p = 0; p < NPART; ++p) {
      cur[(size_t)p * H + i] = running;                   // read-only base for fill
      running += (int)(hist[(size_t)p * H + i] >> 40);
    }
  }
  if (i == 0) off[n] = E;
}

// ---------------- GEMM wave body (fragment-order bf16 A): 16-row x 64-col, K=512 ----
__device__ __forceinline__ void gemm_wave_bf(
    const u16* __restrict__ A, const short8* __restrict__ BF,
    u16* __restrict__ C, int M, int tile) {
  const int lane = threadIdx.x & 63;
  const u16* abase = A + (size_t)tile * 8192 + lane * 8;
  const short8* bbase = BF + lane;

  short8 pa[4];
  short8 pb[2][4];
  #pragma unroll
  for (int s = 0; s < 4; ++s)
    pa[s] = *(const short8*)(abase + s * 512);
  #pragma unroll
  for (int s = 0; s < 2; ++s)
    #pragma unroll
    for (int j = 0; j < 4; ++j)
      pb[s][j] = bbase[(s * 4 + j) * 64];
  __builtin_amdgcn_sched_barrier(0);        // prologue loads stay up-front

  floatx4 acc[4];
  #pragma unroll
  for (int j = 0; j < 4; ++j) acc[j] = (floatx4){0.f, 0.f, 0.f, 0.f};

  #pragma unroll
  for (int s = 0; s < 16; ++s) {
    const int sa = s & 3;
    const int sb = s & 1;
    short8 af = pa[sa];
    acc[0] = __builtin_amdgcn_mfma_f32_16x16x32_bf16(af, pb[sb][0], acc[0], 0, 0, 0);
    acc[1] = __builtin_amdgcn_mfma_f32_16x16x32_bf16(af, pb[sb][1], acc[1], 0, 0, 0);
    acc[2] = __builtin_amdgcn_mfma_f32_16x16x32_bf16(af, pb[sb][2], acc[2], 0, 0, 0);
    acc[3] = __builtin_amdgcn_mfma_f32_16x16x32_bf16(af, pb[sb][3], acc[3], 0, 0, 0);
    if (s + 4 < 16)
      pa[sa] = *(const short8*)(abase + (s + 4) * 512);
    if (s + 2 < 16) {
      #pragma unroll
      for (int j = 0; j < 4; ++j)
        pb[sb][j] = bbase[((s + 2) * 4 + j) * 64];
    }
    __builtin_amdgcn_sched_barrier(0);      // refills can't sink past next MFMAs
  }

  const int srow = tile * 16 + (lane >> 4) * 4;
  const int scol = lane & 15;
  #pragma unroll
  for (int i = 0; i < 4; ++i) {
    int rr = srow + i;
    if (rr < M) {
      #pragma unroll
      for (int j = 0; j < 4; ++j)
        C[(size_t)rr * 64 + j * 16 + scol] = f2bfu(acc[j][i]);
    }
  }
}

// ---------------- FUSED B: full GEMM (frag-order bf16 A)  ||  atomic-free fill ----
__global__ __launch_bounds__(256, 4) void k_fusedB(
    const u16* __restrict__ Abf, const short8* __restrict__ BF,
    u16* __restrict__ C, int M, int nbT, int S,
    const int* __restrict__ rowi, const int* __restrict__ coli,
    const float* __restrict__ w,
    const int* __restrict__ rank, const float* __restrict__ dinv,
    const int* __restrict__ cur, unsigned* __restrict__ pairs,
    int H, int E) {
  const int q = blockIdx.x / (S + 1);
  const int r = blockIdx.x % (S + 1);
  if (r == 0) {
    int tile = q * 4 + (threadIdx.x >> 6);
    if (tile < nbT) gemm_wave_bf(Abf, BF, C, M, tile);
  } else {
    int f = q * S + (r - 1);                 // edge-block index (p = f & 7)
    int e = f * 256 + threadIdx.x;
    if (e >= E) return;
    int p = f & (NPART - 1);
    int c = coli[e];
    int rr = rowi[e];
    int pos = cur[(size_t)p * H + c] + rank[e];
    pairs[pos] = ((unsigned)rr << 16) | (u16)f2bf(dinv[rr] * w[e] * dinv[c]);
  }
}

// ---------------- per-node gather row (64 lanes, lane = feature), returns f32 ----------
__device__ __forceinline__ float gather_row(
    const int* __restrict__ off, const unsigned* __restrict__ pairs,
    const float* __restrict__ dinv, const u16* __restrict__ xw,
    const float* __restrict__ bias, int c, int lane) {
  float s = dinv[c]; s *= s;
  float acc = fmaf(bf2f(xw[(size_t)c * 64 + lane]), s, bias[lane]);
  int i = off[c], end = off[c + 1];
  for (; i + 7 < end; i += 8) {
    unsigned p[8];
    float v[8];
    #pragma unroll
    for (int t = 0; t < 8; ++t) p[t] = pairs[i + t];
    #pragma unroll
    for (int t = 0; t < 8; ++t)
      v[t] = bf2f(xw[(size_t)(p[t] >> 16) * 64 + lane]);
    #pragma unroll
    for (int t = 0; t < 8; ++t)
      acc = fmaf(v[t], __uint_as_float((p[t] & 0xffffu) << 16), acc);
  }
  for (; i + 1 < end; i += 2) {
    unsigned p0 = pairs[i], p1 = pairs[i + 1];
    float v0 = bf2f(xw[(size_t)(p0 >> 16) * 64 + lane]);
    float v1 = bf2f(xw[(size_t)(p1 >> 16) * 64 + lane]);
    acc = fmaf(v0, __uint_as_float((p0 & 0xffffu) << 16), acc);
    acc = fmaf(v1, __uint_as_float((p1 & 0xffffu) << 16), acc);
  }
  if (i < end) {
    unsigned p = pairs[i];
    acc = fmaf(bf2f(xw[(size_t)(p >> 16) * 64 + lane]),
               __uint_as_float((p & 0xffffu) << 16), acc);
  }
  return acc;
}

// ---------------- FUSED gather1 + layer-2 GEMM: h1=relu(conv) -> xw2=h1@W2 ----------
// 16-node block: 4 waves x 4 nodes gather (full occupancy: 3125 blocks), h1 rows
// to LDS bf16 [16][72] (2-way max), 1 barrier, each wave MFMAs its 16-col slice.
__global__ __launch_bounds__(256, 4) void k_gconv2(
    const int* __restrict__ off, const unsigned* __restrict__ pairs,
    const float* __restrict__ dinv, const u16* __restrict__ xw1,
    const float* __restrict__ b1, const short8* __restrict__ BF2,
    u16* __restrict__ xw2, int n) {
  __shared__ u16 Ls[16 * 72];
  const int t = threadIdx.x;
  const int lane = t & 63;
  const int w = t >> 6;
  const int tile = blockIdx.x;
  #pragma unroll
  for (int i = 0; i < 4; ++i) {
    int ln = w * 4 + i;
    int c = tile * 16 + ln;
    float acc = 0.f;
    if (c < n) acc = gather_row(off, pairs, dinv, xw1, b1, c, lane);
    acc = fmaxf(acc, 0.f);                  // relu before bf16 round == ref order
    Ls[ln * 72 + lane] = f2bfu(acc);
  }
  __syncthreads();
  short8 a0 = *(const short8*)(Ls + (lane & 15) * 72 + ((lane >> 4) << 3));
  short8 a1 = *(const short8*)(Ls + (lane & 15) * 72 + 32 + ((lane >> 4) << 3));
  short8 b0 = BF2[(0 * 4 + w) * 64 + lane];
  short8 bb1 = BF2[(1 * 4 + w) * 64 + lane];
  floatx4 acc4 = (floatx4){0.f, 0.f, 0.f, 0.f};
  acc4 = __builtin_amdgcn_mfma_f32_16x16x32_bf16(a0, b0, acc4, 0, 0, 0);
  acc4 = __builtin_amdgcn_mfma_f32_16x16x32_bf16(a1, bb1, acc4, 0, 0, 0);
  const int srow = tile * 16 + (lane >> 4) * 4;
  const int scol = w * 16 + (lane & 15);
  #pragma unroll
  for (int i = 0; i < 4; ++i) {
    int rr = srow + i;
    if (rr < n) xw2[(size_t)rr * 64 + scol] = f2bfu(acc4[i]);
  }
}

// ---------------- FUSED gather2 + FC heads: h2=conv -> (pred, pred_cluster) ---------
// Same 16-node structure; h2 kept f32 in LDS (skips a bf16 round). Ws/bias staged
// up-front (overlaps gather loads); 256 threads x 3 output cols each.
__global__ __launch_bounds__(256, 4) void k_gfc(
    const int* __restrict__ off, const unsigned* __restrict__ pairs,
    const float* __restrict__ dinv, const u16* __restrict__ xw2,
    const float* __restrict__ b2,
    const float* __restrict__ fW1, const float* __restrict__ fb1,
    const float* __restrict__ fW2, const float* __restrict__ fb2,
    float* __restrict__ out, int n) {
  __shared__ float Hs[16][68];
  __shared__ float Ws[64][48];
  __shared__ float bs[48];
  const int t = threadIdx.x;
  const int lane = t & 63;
  const int w = t >> 6;
  const int tile = blockIdx.x;
  for (int f = t; f < 64 * 48; f += 256) {
    int k = f / 48, c = f - k * 48;
    Ws[k][c] = (c < 16) ? fW1[k * 16 + c] : fW2[k * 32 + (c - 16)];
  }
  if (t < 48) bs[t] = (t < 16) ? fb1[t] : fb2[t - 16];
  #pragma unroll
  for (int i = 0; i < 4; ++i) {
    int ln = w * 4 + i;
    int c = tile * 16 + ln;
    float acc = 0.f;
    if (c < n) acc = gather_row(off, pairs, dinv, xw2, b2, c, lane);
    Hs[ln][lane] = acc;                     // f32 (no bf16 round -> more accurate)
  }
  __syncthreads();
  const int r = t >> 4;                     // 0..15
  const int c0 = (t & 15) * 3;              // 0,3,...,45
  float a0 = 0.f, a1 = 0.f, a2 = 0.f;
  #pragma unroll 16
  for (int k = 0; k < 64; ++k) {
    float hv = Hs[r][k];
    a0 = fmaf(hv, Ws[k][c0], a0);
    a1 = fmaf(hv, Ws[k][c0 + 1], a1);
    a2 = fmaf(hv, Ws[k][c0 + 2], a2);
  }
  int rr = tile * 16 + r;
  if (rr < n) {
    float v[3] = {a0 + bs[c0], a1 + bs[c0 + 1], a2 + bs[c0 + 2]};
    #pragma unroll
    for (int j = 0; j < 3; ++j) {
      int c = c0 + j;
      if (c < 16) out[(size_t)rr * 16 + c] = v[j];
      else out[(size_t)n * 16 + (size_t)rr * 32 + (c - 16)] = v[j];
    }
  }
}

extern "C" void kernel_launch(void* const* d_in, const int* in_sizes, int n_in,
                              void* d_out, int out_size, void* d_ws, size_t ws_size,
                              hipStream_t stream) {
  const float* x    = (const float*)d_in[0];
  const int*   ei   = (const int*)d_in[1];
  const float* ew   = (const float*)d_in[2];
  const float* W1   = (const float*)d_in[3];
  const float* b1   = (const float*)d_in[4];
  const float* W2   = (const float*)d_in[5];
  const float* b2   = (const float*)d_in[6];
  const float* fW1  = (const float*)d_in[7];
  const float* fb1  = (const float*)d_in[8];
  const float* fW2  = (const float*)d_in[9];
  const float* fb2  = (const float*)d_in[10];
  float* out = (float*)d_out;

  const int N = in_sizes[0] / N_FEAT;      // 50000 < 65536 (16-bit src pack)
  const int E = in_sizes[2];
  const int H = (N + 63) & ~63;
  const int* row = ei;
  const int* col = ei + E;

  char* ws = (char*)d_ws;
  float*              dinv = (float*)(ws + 0x000000);               // N f
  int*                off  = (int*)  (ws + 0x080000);               // N+1 i
  int*                bsum = (int*)  (ws + 0x0C0000);
  short*              BF1  = (short*)(ws + 0x0C8000);               // 64KB frag-order B1
  short*              BF2  = (short*)(ws + 0x0DA000);               // 8KB frag-order B2
  unsigned long long* hist = (unsigned long long*)(ws + 0x100000);  // 8*H u64 (3.2MB)
  int*                cur  = (int*)  (ws + 0x500000);               // 8*H i (1.6MB)
  unsigned*           pairs= (unsigned*)(ws + 0x6C0000);            // E u32 (3.2MB)
  int*                rank = (int*)  (ws + 0xA00000);               // E i (3.2MB)
  u16*                bufA = (u16*)  (ws + 0xD40000);               // N*64 bf16 (xw1)
  u16*                bufB = (u16*)  (ws + 0x1980000);              // N*64 bf16 (xw2)
  u16*                xbf  = (u16*)  (ws + 0x2400000);              // nbT*8192 bf16 (51.2MB)

  const int nbN  = (N + 255) / 256;
  const int nbE  = (E + 255) / 256;        // 3125 edge blocks
  const int nbT  = (N + 15) / 16;          // 3125 16-row tiles
  const int nH16 = NPART * H / 2;          // hist size in uint4 units
  const int nbZ  = (nH16 + 255) / 256;

  // dispatch-A geometry: 1 edge block : 1 transpose-tile block
  const int QA = (nbE > nbT) ? nbE : nbT;
  // dispatch-B geometry: full gemm || fill
  const int GB = (nbT + 3) / 4;            // 782
  const int SB = (nbE + GB - 1) / GB;      // 4

  // ---- init: zero hist + weight pre-pack (one dispatch) ----
  k_init<<<nbZ + 18, 256, 0, stream>>>((uint4*)hist, nH16, W1, BF1, W2, BF2, nbZ);

  // ---- A: degcnt (+rank) || x -> xbf (bf16, fragment order) ----
  k_fusedA<<<QA * 2, 256, 0, stream>>>(x, xbf, N, col, ew, hist, rank, H, E, nbE, nbT);

  // ---- normalization + CSR offsets ----
  k_redscan<<<nbN, 256, 0, stream>>>(hist, H, dinv, off, bsum, N);
  k_scan3_initcur<<<nbN, 256, 0, stream>>>(off, bsum, hist, H, cur, N, E, nbN);

  // ---- B: full GEMM (contiguous frag-order A) || atomic-free fill ----
  k_fusedB<<<GB * (SB + 1), 256, 0, stream>>>(
      xbf, (const short8*)BF1, bufA, N, nbT, SB,
      row, col, ew, rank, dinv, cur, pairs, H, E);

  // ---- gather1 + layer-2 GEMM fused: xw2 = relu(conv(xw1)) @ W2 ----
  k_gconv2<<<nbT, 256, 0, stream>>>(off, pairs, dinv, bufA, b1,
                                    (const short8*)BF2, bufB, N);

  // ---- gather2 + FC heads fused: out = fc(conv(xw2)) ----
  k_gfc<<<nbT, 256, 0, stream>>>(off, pairs, dinv, bufB, b2,
                                 fW1, fb1, fW2, fb2, out, N);
}